// Round 2
// baseline (1066.733 us; speedup 1.0000x reference)
//
#include <hip/hip_runtime.h>
#include <hip/hip_fp16.h>
#include <math.h>

#define NN 50000
#define EE 800000
#define DD 512
#define HH 256
#define KK 16

// ---------------- utility ----------------
__global__ void zero_kernel(int* __restrict__ p, int n) {
    int i = blockIdx.x * blockDim.x + threadIdx.x;
    if (i < n) p[i] = 0;
}

__global__ void count_kernel(const int* __restrict__ src, const int* __restrict__ dst,
                             int* __restrict__ indeg, int* __restrict__ outdeg) {
    int e = blockIdx.x * blockDim.x + threadIdx.x;
    if (e < EE) {
        atomicAdd(&indeg[dst[e]], 1);
        atomicAdd(&outdeg[src[e]], 1);
    }
}

__global__ void node_prep(const int* __restrict__ indeg, const int* __restrict__ outdeg,
                          float* __restrict__ dis, float* __restrict__ degf) {
    int n = blockIdx.x * blockDim.x + threadIdx.x;
    if (n < NN) {
        dis[n]  = 1.0f / sqrtf(1.0f + (float)indeg[n]);
        degf[n] = (float)outdeg[n];
    }
}

// single-block exclusive scan of in[0..n) -> out[0..n], out[n]=total
__global__ void scan_excl(const int* __restrict__ in, int* __restrict__ out, int n) {
    __shared__ int tile[256];
    __shared__ int carry_s;
    int t = threadIdx.x;
    if (t == 0) carry_s = 0;
    __syncthreads();
    for (int base = 0; base < n; base += 256) {
        int v = (base + t < n) ? in[base + t] : 0;
        tile[t] = v;
        __syncthreads();
        for (int off = 1; off < 256; off <<= 1) {
            int x = (t >= off) ? tile[t - off] : 0;
            __syncthreads();
            tile[t] += x;
            __syncthreads();
        }
        int incl = tile[t];
        int total = tile[255];
        int carry = carry_s;
        if (base + t < n) out[base + t] = carry + incl - v;
        __syncthreads();
        if (t == 0) carry_s = carry + total;
        __syncthreads();
    }
    if (t == 0) out[n] = carry_s;
}

__global__ void scatter_kernel(const int* __restrict__ src, const int* __restrict__ dst,
                               const int* __restrict__ off, int* __restrict__ cur,
                               int* __restrict__ nbr) {
    int e = blockIdx.x * blockDim.x + threadIdx.x;
    if (e < EE) {
        int s = src[e], d = dst[e];
        int p = atomicAdd(&cur[d], 1);
        nbr[off[d] + p] = s;
    }
}

// ---------------- GEMM 128x128x8, 8x8 microtile, 256 threads ----------------
// C[M,Nn] = A[M,Kk] @ B[Kk,Nn]; A row-major (f32 or f16), B f32 row-major,
// C stored as f16. Requires Nn%128==0, Kk%8==0.
__device__ inline float4 load4(const float* p) { return *(const float4*)p; }
__device__ inline float4 load4(const __half* p) {
    const __half2* h = (const __half2*)p;  // 8B-aligned (4-half aligned callers)
    float2 a = __half22float2(h[0]);
    float2 b = __half22float2(h[1]);
    return make_float4(a.x, a.y, b.x, b.y);
}

template <typename TA>
__global__ __launch_bounds__(256) void sgemm128(const TA* __restrict__ A,
                                                const float* __restrict__ B,
                                                __half* __restrict__ C,
                                                int M, int Nn, int Kk) {
    __shared__ float As[8][128];
    __shared__ float Bs[8][128];
    int t = threadIdx.x;
    int row0 = blockIdx.y * 128;
    int col0 = blockIdx.x * 128;
    int tx = t % 16, ty = t / 16;
    float cacc[8][8] = {};
    int am = t >> 1;        // 0..127
    int ak = (t & 1) * 4;   // 0 or 4
    int bk = t >> 5;        // 0..7
    int bn = (t & 31) * 4;  // 0..124
    for (int k0 = 0; k0 < Kk; k0 += 8) {
        float4 av = make_float4(0.f, 0.f, 0.f, 0.f);
        if (row0 + am < M) av = load4(A + (size_t)(row0 + am) * Kk + k0 + ak);
        As[ak + 0][am] = av.x;
        As[ak + 1][am] = av.y;
        As[ak + 2][am] = av.z;
        As[ak + 3][am] = av.w;
        float4 bv = *(const float4*)(B + (size_t)(k0 + bk) * Nn + col0 + bn);
        *(float4*)(&Bs[bk][bn]) = bv;
        __syncthreads();
#pragma unroll
        for (int kk = 0; kk < 8; kk++) {
            float a[8], b[8];
#pragma unroll
            for (int i = 0; i < 8; i++) a[i] = As[kk][ty * 8 + i];
#pragma unroll
            for (int i = 0; i < 8; i++) b[i] = Bs[kk][tx * 8 + i];
#pragma unroll
            for (int i = 0; i < 8; i++)
#pragma unroll
                for (int j = 0; j < 8; j++) cacc[i][j] += a[i] * b[j];
        }
        __syncthreads();
    }
    for (int i = 0; i < 8; i++) {
        int r = row0 + ty * 8 + i;
        if (r < M) {
            __half hv[8];
#pragma unroll
            for (int j = 0; j < 8; j++) hv[j] = __float2half(cacc[i][j]);
            *(float4*)(C + (size_t)r * Nn + col0 + tx * 8) = *(float4*)hv;  // 16B store
        }
    }
}

// ---------------- aggregation + bias + SELU (+optional skip), one block per node ----------------
__global__ __launch_bounds__(256) void agg_selu(const __half* __restrict__ T,
                                                const float* __restrict__ dis,
                                                const int* __restrict__ off,
                                                const int* __restrict__ nbr,
                                                const float* __restrict__ bias,
                                                const __half* skip, __half* out) {
    int n = blockIdx.x;
    int c = threadIdx.x;
    float dn = dis[n];
    float acc = dn * dn * __half2float(T[(size_t)n * HH + c]);
    int s0 = off[n], s1 = off[n + 1];
    __shared__ int sid[256];
    __shared__ float sds[256];
    for (int base = s0; base < s1; base += 256) {
        int cnt = min(256, s1 - base);
        if (c < cnt) {
            int s = nbr[base + c];
            sid[c] = s;
            sds[c] = dis[s] * dn;
        }
        __syncthreads();
        for (int j = 0; j < cnt; j++)
            acc += sds[j] * __half2float(T[(size_t)sid[j] * HH + c]);
        __syncthreads();
    }
    float v = acc + bias[c];
    const float scale = 1.0507009873554805f;
    const float alpha = 1.6732632423543772f;
    float r = v > 0.f ? scale * v : scale * alpha * expm1f(v);
    if (skip) r += __half2float(skip[(size_t)n * HH + c]);
    out[(size_t)n * HH + c] = __float2half(r);
}

// ---------------- assignment head: logits -> softmax -> out + loss partials ----------------
// 16 nodes per block, thread t: k = t&15, node-local = t>>4
__global__ __launch_bounds__(256) void assign_kernel(const __half* __restrict__ X,
                                                     const float* __restrict__ Wa,
                                                     const float* __restrict__ ba,
                                                     const float* __restrict__ degf,
                                                     float* __restrict__ out_assign,
                                                     float* __restrict__ scal) {
    __shared__ float sWa[HH * KK];   // 16 KB
    __shared__ float sX[16][HH];     // 16 KB
    __shared__ float scs[KK], sdS[KK], sent_s;
    int t = threadIdx.x;
    int nb = blockIdx.x * 16;
    for (int i = t; i < HH * KK; i += 256) sWa[i] = Wa[i];
    for (int r = 0; r < 16; r++) sX[r][t] = __half2float(X[(size_t)(nb + r) * HH + t]);
    if (t < KK) { scs[t] = 0.f; sdS[t] = 0.f; }
    if (t == 0) sent_s = 0.f;
    __syncthreads();

    int k = t & 15, nl = t >> 4;
    float logit = ba[k];
    for (int c = 0; c < HH; c++) logit += sX[nl][c] * sWa[c * KK + k];

    float mx = logit;
    for (int o = 1; o < 16; o <<= 1) mx = fmaxf(mx, __shfl_xor(mx, o, 16));
    float e = expf(logit - mx);
    float sum = e;
    for (int o = 1; o < 16; o <<= 1) sum += __shfl_xor(sum, o, 16);
    float a = e / sum;
    int node = nb + nl;
    out_assign[(size_t)node * KK + k] = a;

    atomicAdd(&scs[k], a);
    atomicAdd(&sdS[k], degf[node] * a);
    float ent = a * logf(a + 1e-8f);
    for (int o = 32; o >= 1; o >>= 1) ent += __shfl_xor(ent, o);
    if ((t & 63) == 0) atomicAdd(&sent_s, ent);
    __syncthreads();
    if (t < KK) {
        atomicAdd(&scal[t], scs[t]);
        atomicAdd(&scal[16 + t], sdS[t]);
    }
    if (t == 0) atomicAdd(&scal[33], sent_s);
}

// ---------------- fused trace(S^T A S) = sum over edges <a_src, a_dst> ----------------
__global__ __launch_bounds__(256) void edge_trace(const int* __restrict__ src,
                                                  const int* __restrict__ dst,
                                                  const float* __restrict__ assign,
                                                  float* __restrict__ scal) {
    int e = blockIdx.x * blockDim.x + threadIdx.x;
    float p = 0.f;
    if (e < EE) {
        int s = src[e], d = dst[e];
        const float4* pa = (const float4*)(assign + (size_t)s * KK);
        const float4* pb = (const float4*)(assign + (size_t)d * KK);
#pragma unroll
        for (int i = 0; i < 4; i++) {
            float4 x = pa[i], y = pb[i];
            p += x.x * y.x + x.y * y.y + x.z * y.z + x.w * y.w;
        }
    }
    for (int o = 32; o >= 1; o >>= 1) p += __shfl_xor(p, o);
    __shared__ float sp;
    if (threadIdx.x == 0) sp = 0.f;
    __syncthreads();
    if ((threadIdx.x & 63) == 0) atomicAdd(&sp, p);
    __syncthreads();
    if (threadIdx.x == 0) atomicAdd(&scal[32], sp);
}

// ---------------- pooled partial: pool_acc[k][d] += sum_n a[n][k]*emb[n][d] ----------------
#define PCHUNK 250
__global__ __launch_bounds__(256) void pooled_partial(const float* __restrict__ emb,
                                                      const float* __restrict__ assign,
                                                      float* __restrict__ pool_acc) {
    int d = blockIdx.x * 256 + threadIdx.x;
    int c0 = blockIdx.y * PCHUNK;
    float acc[KK];
#pragma unroll
    for (int k = 0; k < KK; k++) acc[k] = 0.f;
    __shared__ float sa[128 * KK];  // 8 KB
    for (int sub = 0; sub < PCHUNK; sub += 128) {
        int cnt = min(128, PCHUNK - sub);
        for (int i = threadIdx.x; i < cnt * KK; i += 256)
            sa[i] = assign[(size_t)(c0 + sub) * KK + i];
        __syncthreads();
        for (int j = 0; j < cnt; j++) {
            float ev = emb[(size_t)(c0 + sub + j) * DD + d];
#pragma unroll
            for (int k = 0; k < KK; k++) acc[k] += sa[j * KK + k] * ev;
        }
        __syncthreads();
    }
#pragma unroll
    for (int k = 0; k < KK; k++) atomicAdd(&pool_acc[k * DD + d], acc[k]);
}

// ---------------- finalize: pooled normalize + scalar losses ----------------
__global__ void finalize(const float* __restrict__ pool_acc, const float* __restrict__ scal,
                         float* __restrict__ out) {
    int bx = blockIdx.x, t = threadIdx.x;
    if (bx < 32) {
        int i = bx * 256 + t;  // 0..8191
        int k = i / DD;
        out[800000 + i] = pool_acc[i] / (scal[k] + 1e-8f);
    } else if (t == 0) {
        float cs2 = 0.f, ds2 = 0.f;
        for (int k = 0; k < KK; k++) {
            cs2 += scal[k] * scal[k];
            ds2 += scal[16 + k] * scal[16 + k];
        }
        float two_m = (float)EE;  // sum(degrees) == E, 2m == E
        float normalizer = ds2 / two_m;
        float trace = scal[32];
        float spectral = -(trace - (float)KK * normalizer) / two_m;
        float collapse = sqrtf(cs2) / (float)NN * 4.0f - 1.0f;  // sqrt(K)=4
        float entl = 0.1f * scal[33] / (float)NN;
        out[808192] = spectral;
        out[808193] = collapse;  // COLLAPSE_REG = 1.0
        out[808194] = spectral + collapse + entl;
        out[808195] = entl;
    }
}

extern "C" void kernel_launch(void* const* d_in, const int* in_sizes, int n_in,
                              void* d_out, int out_size, void* d_ws, size_t ws_size,
                              hipStream_t stream) {
    const float* emb = (const float*)d_in[0];
    const int* esrc  = (const int*)d_in[1];
    const int* edst  = (const int*)d_in[2];
    const float* W1  = (const float*)d_in[3];
    const float* b1  = (const float*)d_in[4];
    const float* W2  = (const float*)d_in[5];
    const float* b2  = (const float*)d_in[6];
    const float* Wa  = (const float*)d_in[7];
    const float* ba  = (const float*)d_in[8];
    float* out = (float*)d_out;

    // workspace layout (4B units unless noted) — total ~55.6 MB
    int* indeg      = (int*)d_ws;            // 50000
    int* outdeg     = indeg + 50000;         // 50000
    int* cur        = outdeg + 50000;        // 50000
    float* pool_acc = (float*)(cur + 50000); // 8192
    float* scal     = pool_acc + 8192;       // 64 (cs[16], dS[16], trace, ent)
    int* off        = (int*)(scal + 64);     // 50001 (+pad to 50004)
    int* nbr        = off + 50004;           // 800000
    float* dis      = (float*)(nbr + 800000);// 50000
    float* degf     = dis + 50000;           // 50000
    __half* T       = (__half*)(degf + 50000);   // 50000*256 f16 (25.6 MB)
    __half* Hb      = T + (size_t)NN * HH;       // 50000*256 f16 (25.6 MB)

    // zero the atomically-accumulated region: indeg/outdeg/cur/pool_acc/scal
    zero_kernel<<<dim3(619), 256, 0, stream>>>((int*)d_ws, 158256);
    count_kernel<<<dim3(3125), 256, 0, stream>>>(esrc, edst, indeg, outdeg);
    node_prep<<<dim3(196), 256, 0, stream>>>(indeg, outdeg, dis, degf);
    scan_excl<<<1, 256, 0, stream>>>(indeg, off, NN);
    scatter_kernel<<<dim3(3125), 256, 0, stream>>>(esrc, edst, off, cur, nbr);

    // conv1: T = emb @ W1 ; Hb = selu(Ahat*T + b1)
    sgemm128<float><<<dim3(2, 391), 256, 0, stream>>>(emb, W1, T, NN, HH, DD);
    agg_selu<<<dim3(NN), 256, 0, stream>>>(T, dis, off, nbr, b1, nullptr, Hb);

    // conv2: T = Hb @ W2 ; Hb = selu(Ahat*T + b2) + Hb (skip, in place)
    sgemm128<__half><<<dim3(2, 391), 256, 0, stream>>>(Hb, W2, T, NN, HH, HH);
    agg_selu<<<dim3(NN), 256, 0, stream>>>(T, dis, off, nbr, b2, Hb, Hb);

    // head: assignments -> d_out[0..800000), loss partials
    assign_kernel<<<dim3(3125), 256, 0, stream>>>(Hb, Wa, ba, degf, out, scal);
    edge_trace<<<dim3(3125), 256, 0, stream>>>(esrc, edst, out, scal);
    pooled_partial<<<dim3(2, 200), 256, 0, stream>>>(emb, out, pool_acc);
    finalize<<<dim3(33), 256, 0, stream>>>(pool_acc, scal, out);
}

// Round 3
// 705.439 us; speedup vs baseline: 1.5122x; 1.5122x over previous
//
#include <hip/hip_runtime.h>
#include <hip/hip_fp16.h>
#include <math.h>

#define NN 50000
#define EE 800000
#define DD 512
#define HH 256
#define KK 16
#define NB_SCAN 196  // ceil(NN/256)

typedef _Float16 half8_t __attribute__((ext_vector_type(8)));
typedef float f32x4 __attribute__((ext_vector_type(4)));

// ---------------- utility ----------------
__global__ void zero_kernel(int* __restrict__ p, int n) {
    int i = blockIdx.x * blockDim.x + threadIdx.x;
    if (i < n) p[i] = 0;
}

__global__ void count_kernel(const int* __restrict__ src, const int* __restrict__ dst,
                             int* __restrict__ indeg, int* __restrict__ outdeg) {
    int e = blockIdx.x * blockDim.x + threadIdx.x;
    if (e < EE) {
        atomicAdd(&indeg[dst[e]], 1);
        atomicAdd(&outdeg[src[e]], 1);
    }
}

__global__ void node_prep(const int* __restrict__ indeg, const int* __restrict__ outdeg,
                          float* __restrict__ dis, float* __restrict__ degf) {
    int n = blockIdx.x * blockDim.x + threadIdx.x;
    if (n < NN) {
        dis[n]  = 1.0f / sqrtf(1.0f + (float)indeg[n]);
        degf[n] = (float)outdeg[n];
    }
}

// ---------------- 3-phase multi-block exclusive scan ----------------
__global__ void scan_p1(const int* __restrict__ in, int* __restrict__ part, int n) {
    __shared__ int tile[256];
    int t = threadIdx.x;
    int i = blockIdx.x * 256 + t;
    tile[t] = (i < n) ? in[i] : 0;
    __syncthreads();
    for (int o = 128; o > 0; o >>= 1) {
        if (t < o) tile[t] += tile[t + o];
        __syncthreads();
    }
    if (t == 0) part[blockIdx.x] = tile[0];
}

__global__ void scan_p2(int* __restrict__ part, int nb, int* __restrict__ off_end) {
    __shared__ int tile[256];
    int t = threadIdx.x;
    int v = (t < nb) ? part[t] : 0;
    tile[t] = v;
    __syncthreads();
    for (int o = 1; o < 256; o <<= 1) {
        int x = (t >= o) ? tile[t - o] : 0;
        __syncthreads();
        tile[t] += x;
        __syncthreads();
    }
    if (t < nb) part[t] = tile[t] - v;  // exclusive base per block
    if (t == 255) *off_end = tile[255];
}

__global__ void scan_p3(const int* __restrict__ in, const int* __restrict__ part,
                        int* __restrict__ out, int n) {
    __shared__ int tile[256];
    int t = threadIdx.x;
    int i = blockIdx.x * 256 + t;
    int v = (i < n) ? in[i] : 0;
    tile[t] = v;
    __syncthreads();
    for (int o = 1; o < 256; o <<= 1) {
        int x = (t >= o) ? tile[t - o] : 0;
        __syncthreads();
        tile[t] += x;
        __syncthreads();
    }
    if (i < n) out[i] = part[blockIdx.x] + tile[t] - v;
}

__global__ void scatter_kernel(const int* __restrict__ src, const int* __restrict__ dst,
                               const int* __restrict__ off, int* __restrict__ cur,
                               int* __restrict__ nbr) {
    int e = blockIdx.x * blockDim.x + threadIdx.x;
    if (e < EE) {
        int s = src[e], d = dst[e];
        int p = atomicAdd(&cur[d], 1);
        nbr[off[d] + p] = s;
    }
}

// ---------------- weight transpose + f16 convert: Wt[n][k] = W[k][n] ----------------
__global__ void transpose_w(const float* __restrict__ W, __half* __restrict__ Wt,
                            int Kdim, int Ndim) {
    int i = blockIdx.x * 256 + threadIdx.x;
    if (i < Kdim * Ndim) {
        int k = i / Ndim, n = i % Ndim;
        Wt[(size_t)n * Kdim + k] = __float2half(W[i]);
    }
}

// ---------------- MFMA f16 GEMM: C[M,Nn] = A[M,Kk] @ Bt[n][k]^T ----------------
// Block tile 128x128, 4 waves each 64x64 (4x4 grid of 16x16x32 mfma), K-step 32.
// A: f32 or f16 row-major [M][Kk]; Bt: f16 [Nn][Kk] (pre-transposed); C: f16 [M][Nn].
#define APAD 40  // LDS row stride in halves: 80B, 16B-aligned, 2-way bank alias (free)

__device__ inline void load16h(const float* p, _Float16* o) {
#pragma unroll
    for (int i = 0; i < 16; i += 4) {
        float4 v = *(const float4*)(p + i);
        o[i] = (_Float16)v.x; o[i + 1] = (_Float16)v.y;
        o[i + 2] = (_Float16)v.z; o[i + 3] = (_Float16)v.w;
    }
}
__device__ inline void load16h(const __half* p, _Float16* o) {
    uint4 v0 = *(const uint4*)p;
    uint4 v1 = *(const uint4*)(p + 8);
    *(uint4*)o = v0;
    *(uint4*)(o + 8) = v1;
}

template <typename TA>
__global__ __launch_bounds__(256) void mfma_gemm(const TA* __restrict__ A,
                                                 const __half* __restrict__ Bt,
                                                 __half* __restrict__ C,
                                                 int M, int Nn, int Kk) {
    __shared__ _Float16 As[128][APAD];
    __shared__ _Float16 Bs[128][APAD];
    int t = threadIdx.x;
    int wave = t >> 6, lane = t & 63;
    int quad = lane >> 4, l16 = lane & 15;
    int row0 = blockIdx.y * 128, col0 = blockIdx.x * 128;
    int wm = (wave & 1) * 64, wn = (wave >> 1) * 64;

    f32x4 acc[4][4] = {};

    int sr = t >> 1;         // staging row 0..127
    int sk = (t & 1) * 16;   // staging k-offset 0 or 16

    for (int k0 = 0; k0 < Kk; k0 += 32) {
        // stage A tile [128][32]
        {
            _Float16 tmp[16];
            int gr = row0 + sr;
            if (gr < M) {
                load16h(A + (size_t)gr * Kk + k0 + sk, tmp);
            } else {
#pragma unroll
                for (int i = 0; i < 16; i++) tmp[i] = (_Float16)0.f;
            }
            *(uint4*)&As[sr][sk] = *(uint4*)tmp;
            *(uint4*)&As[sr][sk + 8] = *(uint4*)(tmp + 8);
        }
        // stage B tile [128][32] from Bt rows (col0+sr)
        {
            _Float16 tmp[16];
            load16h(Bt + (size_t)(col0 + sr) * Kk + k0 + sk, tmp);
            *(uint4*)&Bs[sr][sk] = *(uint4*)tmp;
            *(uint4*)&Bs[sr][sk + 8] = *(uint4*)(tmp + 8);
        }
        __syncthreads();

        half8_t af[4], bf[4];
#pragma unroll
        for (int mi = 0; mi < 4; mi++)
            af[mi] = *(const half8_t*)&As[wm + mi * 16 + l16][quad * 8];
#pragma unroll
        for (int ni = 0; ni < 4; ni++)
            bf[ni] = *(const half8_t*)&Bs[wn + ni * 16 + l16][quad * 8];
#pragma unroll
        for (int mi = 0; mi < 4; mi++)
#pragma unroll
            for (int ni = 0; ni < 4; ni++)
                acc[mi][ni] = __builtin_amdgcn_mfma_f32_16x16x32_f16(
                    af[mi], bf[ni], acc[mi][ni], 0, 0, 0);
        __syncthreads();
    }

    // write C: tile (mi,ni), reg r -> row=quad*4+r, col=l16
#pragma unroll
    for (int mi = 0; mi < 4; mi++) {
#pragma unroll
        for (int r = 0; r < 4; r++) {
            int rr = row0 + wm + mi * 16 + quad * 4 + r;
            if (rr < M) {
#pragma unroll
                for (int ni = 0; ni < 4; ni++) {
                    C[(size_t)rr * Nn + col0 + wn + ni * 16 + l16] =
                        __float2half(acc[mi][ni][r]);
                }
            }
        }
    }
}

// ---------------- aggregation + bias + SELU (+optional skip), one block per node ----------------
__global__ __launch_bounds__(256) void agg_selu(const __half* __restrict__ T,
                                                const float* __restrict__ dis,
                                                const int* __restrict__ off,
                                                const int* __restrict__ nbr,
                                                const float* __restrict__ bias,
                                                const __half* skip, __half* out) {
    int n = blockIdx.x;
    int c = threadIdx.x;
    float dn = dis[n];
    float acc = dn * dn * __half2float(T[(size_t)n * HH + c]);
    int s0 = off[n], s1 = off[n + 1];
    __shared__ int sid[256];
    __shared__ float sds[256];
    for (int base = s0; base < s1; base += 256) {
        int cnt = min(256, s1 - base);
        if (c < cnt) {
            int s = nbr[base + c];
            sid[c] = s;
            sds[c] = dis[s] * dn;
        }
        __syncthreads();
        for (int j = 0; j < cnt; j++)
            acc += sds[j] * __half2float(T[(size_t)sid[j] * HH + c]);
        __syncthreads();
    }
    float v = acc + bias[c];
    const float scale = 1.0507009873554805f;
    const float alpha = 1.6732632423543772f;
    float r = v > 0.f ? scale * v : scale * alpha * expm1f(v);
    if (skip) r += __half2float(skip[(size_t)n * HH + c]);
    out[(size_t)n * HH + c] = __float2half(r);
}

// ---------------- assignment head: logits -> softmax -> out + loss partials ----------------
__global__ __launch_bounds__(256) void assign_kernel(const __half* __restrict__ X,
                                                     const float* __restrict__ Wa,
                                                     const float* __restrict__ ba,
                                                     const float* __restrict__ degf,
                                                     float* __restrict__ out_assign,
                                                     float* __restrict__ scal) {
    __shared__ float sWa[HH * KK];   // 16 KB
    __shared__ float sX[16][HH];     // 16 KB
    __shared__ float scs[KK], sdS[KK], sent_s;
    int t = threadIdx.x;
    int nb = blockIdx.x * 16;
    for (int i = t; i < HH * KK; i += 256) sWa[i] = Wa[i];
    for (int r = 0; r < 16; r++) sX[r][t] = __half2float(X[(size_t)(nb + r) * HH + t]);
    if (t < KK) { scs[t] = 0.f; sdS[t] = 0.f; }
    if (t == 0) sent_s = 0.f;
    __syncthreads();

    int k = t & 15, nl = t >> 4;
    float logit = ba[k];
    for (int c = 0; c < HH; c++) logit += sX[nl][c] * sWa[c * KK + k];

    float mx = logit;
    for (int o = 1; o < 16; o <<= 1) mx = fmaxf(mx, __shfl_xor(mx, o, 16));
    float e = expf(logit - mx);
    float sum = e;
    for (int o = 1; o < 16; o <<= 1) sum += __shfl_xor(sum, o, 16);
    float a = e / sum;
    int node = nb + nl;
    out_assign[(size_t)node * KK + k] = a;

    atomicAdd(&scs[k], a);
    atomicAdd(&sdS[k], degf[node] * a);
    float ent = a * logf(a + 1e-8f);
    for (int o = 32; o >= 1; o >>= 1) ent += __shfl_xor(ent, o);
    if ((t & 63) == 0) atomicAdd(&sent_s, ent);
    __syncthreads();
    if (t < KK) {
        atomicAdd(&scal[t], scs[t]);
        atomicAdd(&scal[16 + t], sdS[t]);
    }
    if (t == 0) atomicAdd(&scal[33], sent_s);
}

// ---------------- fused trace(S^T A S) = sum over edges <a_src, a_dst> ----------------
__global__ __launch_bounds__(256) void edge_trace(const int* __restrict__ src,
                                                  const int* __restrict__ dst,
                                                  const float* __restrict__ assign,
                                                  float* __restrict__ scal) {
    int e = blockIdx.x * blockDim.x + threadIdx.x;
    float p = 0.f;
    if (e < EE) {
        int s = src[e], d = dst[e];
        const float4* pa = (const float4*)(assign + (size_t)s * KK);
        const float4* pb = (const float4*)(assign + (size_t)d * KK);
#pragma unroll
        for (int i = 0; i < 4; i++) {
            float4 x = pa[i], y = pb[i];
            p += x.x * y.x + x.y * y.y + x.z * y.z + x.w * y.w;
        }
    }
    for (int o = 32; o >= 1; o >>= 1) p += __shfl_xor(p, o);
    __shared__ float sp;
    if (threadIdx.x == 0) sp = 0.f;
    __syncthreads();
    if ((threadIdx.x & 63) == 0) atomicAdd(&sp, p);
    __syncthreads();
    if (threadIdx.x == 0) atomicAdd(&scal[32], sp);
}

// ---------------- pooled partial: pool_acc[k][d] += sum_n a[n][k]*emb[n][d] ----------------
#define PCHUNK 250
__global__ __launch_bounds__(256) void pooled_partial(const float* __restrict__ emb,
                                                      const float* __restrict__ assign,
                                                      float* __restrict__ pool_acc) {
    int d = blockIdx.x * 256 + threadIdx.x;
    int c0 = blockIdx.y * PCHUNK;
    float acc[KK];
#pragma unroll
    for (int k = 0; k < KK; k++) acc[k] = 0.f;
    __shared__ float sa[128 * KK];  // 8 KB
    for (int sub = 0; sub < PCHUNK; sub += 128) {
        int cnt = min(128, PCHUNK - sub);
        for (int i = threadIdx.x; i < cnt * KK; i += 256)
            sa[i] = assign[(size_t)(c0 + sub) * KK + i];
        __syncthreads();
        for (int j = 0; j < cnt; j++) {
            float ev = emb[(size_t)(c0 + sub + j) * DD + d];
#pragma unroll
            for (int k = 0; k < KK; k++) acc[k] += sa[j * KK + k] * ev;
        }
        __syncthreads();
    }
#pragma unroll
    for (int k = 0; k < KK; k++) atomicAdd(&pool_acc[k * DD + d], acc[k]);
}

// ---------------- finalize: pooled normalize + scalar losses ----------------
__global__ void finalize(const float* __restrict__ pool_acc, const float* __restrict__ scal,
                         float* __restrict__ out) {
    int bx = blockIdx.x, t = threadIdx.x;
    if (bx < 32) {
        int i = bx * 256 + t;  // 0..8191
        int k = i / DD;
        out[800000 + i] = pool_acc[i] / (scal[k] + 1e-8f);
    } else if (t == 0) {
        float cs2 = 0.f, ds2 = 0.f;
        for (int k = 0; k < KK; k++) {
            cs2 += scal[k] * scal[k];
            ds2 += scal[16 + k] * scal[16 + k];
        }
        float two_m = (float)EE;  // sum(degrees) == E, 2m == E
        float normalizer = ds2 / two_m;
        float trace = scal[32];
        float spectral = -(trace - (float)KK * normalizer) / two_m;
        float collapse = sqrtf(cs2) / (float)NN * 4.0f - 1.0f;  // sqrt(K)=4
        float entl = 0.1f * scal[33] / (float)NN;
        out[808192] = spectral;
        out[808193] = collapse;  // COLLAPSE_REG = 1.0
        out[808194] = spectral + collapse + entl;
        out[808195] = entl;
    }
}

extern "C" void kernel_launch(void* const* d_in, const int* in_sizes, int n_in,
                              void* d_out, int out_size, void* d_ws, size_t ws_size,
                              hipStream_t stream) {
    const float* emb = (const float*)d_in[0];
    const int* esrc  = (const int*)d_in[1];
    const int* edst  = (const int*)d_in[2];
    const float* W1  = (const float*)d_in[3];
    const float* b1  = (const float*)d_in[4];
    const float* W2  = (const float*)d_in[5];
    const float* b2  = (const float*)d_in[6];
    const float* Wa  = (const float*)d_in[7];
    const float* ba  = (const float*)d_in[8];
    float* out = (float*)d_out;

    // workspace layout (4B units unless noted) — total ~56 MB
    int* indeg      = (int*)d_ws;            // 50000
    int* outdeg     = indeg + 50000;         // 50000
    int* cur        = outdeg + 50000;        // 50000
    float* pool_acc = (float*)(cur + 50000); // 8192
    float* scal     = pool_acc + 8192;       // 64
    int* part       = (int*)(scal + 64);     // 256 (scan partials)
    int* off        = part + 256;            // 50001 (+pad to 50004)
    int* nbr        = off + 50004;           // 800000
    float* dis      = (float*)(nbr + 800000);// 50000
    float* degf     = dis + 50000;           // 50000
    __half* Wt1     = (__half*)(degf + 50000);   // 256*512 f16
    __half* Wt2     = Wt1 + 256 * 512;           // 256*256 f16
    __half* T       = Wt2 + 256 * 256;           // 50000*256 f16 (25.6 MB)
    __half* Hb      = T + (size_t)NN * HH;       // 50000*256 f16 (25.6 MB)

    // zero the atomically-accumulated region: indeg/outdeg/cur/pool_acc/scal
    zero_kernel<<<dim3(619), 256, 0, stream>>>((int*)d_ws, 158256);
    count_kernel<<<dim3(3125), 256, 0, stream>>>(esrc, edst, indeg, outdeg);
    node_prep<<<dim3(196), 256, 0, stream>>>(indeg, outdeg, dis, degf);

    // CSR offsets: 3-phase scan
    scan_p1<<<dim3(NB_SCAN), 256, 0, stream>>>(indeg, part, NN);
    scan_p2<<<dim3(1), 256, 0, stream>>>(part, NB_SCAN, off + NN);
    scan_p3<<<dim3(NB_SCAN), 256, 0, stream>>>(indeg, part, off, NN);
    scatter_kernel<<<dim3(3125), 256, 0, stream>>>(esrc, edst, off, cur, nbr);

    // weights -> f16 transposed
    transpose_w<<<dim3(512), 256, 0, stream>>>(W1, Wt1, DD, HH);
    transpose_w<<<dim3(256), 256, 0, stream>>>(W2, Wt2, HH, HH);

    // conv1: T = emb @ W1 ; Hb = selu(Ahat*T + b1)
    mfma_gemm<float><<<dim3(2, 391), 256, 0, stream>>>(emb, Wt1, T, NN, HH, DD);
    agg_selu<<<dim3(NN), 256, 0, stream>>>(T, dis, off, nbr, b1, nullptr, Hb);

    // conv2: T = Hb @ W2 ; Hb = selu(Ahat*T + b2) + Hb (skip, in place)
    mfma_gemm<__half><<<dim3(2, 391), 256, 0, stream>>>(Hb, Wt2, T, NN, HH, HH);
    agg_selu<<<dim3(NN), 256, 0, stream>>>(T, dis, off, nbr, b2, Hb, Hb);

    // head: assignments -> d_out[0..800000), loss partials
    assign_kernel<<<dim3(3125), 256, 0, stream>>>(Hb, Wa, ba, degf, out, scal);
    edge_trace<<<dim3(3125), 256, 0, stream>>>(esrc, edst, out, scal);
    pooled_partial<<<dim3(2, 200), 256, 0, stream>>>(emb, out, pool_acc);
    finalize<<<dim3(33), 256, 0, stream>>>(pool_acc, scal, out);
}

// Round 4
// 650.874 us; speedup vs baseline: 1.6389x; 1.0838x over previous
//
#include <hip/hip_runtime.h>
#include <hip/hip_fp16.h>
#include <math.h>

#define NN 50000
#define EE 800000
#define DD 512
#define HH 256
#define KK 16
#define NB_SCAN 196  // ceil(NN/256)

typedef _Float16 half8_t __attribute__((ext_vector_type(8)));
typedef float f32x4 __attribute__((ext_vector_type(4)));

// ---------------- utility ----------------
__global__ void zero_kernel(int* __restrict__ p, int n) {
    int i = blockIdx.x * blockDim.x + threadIdx.x;
    if (i < n) p[i] = 0;
}

__global__ void count_kernel(const int* __restrict__ src, const int* __restrict__ dst,
                             int* __restrict__ indeg, int* __restrict__ outdeg) {
    int e = blockIdx.x * blockDim.x + threadIdx.x;
    if (e < EE) {
        atomicAdd(&indeg[dst[e]], 1);
        atomicAdd(&outdeg[src[e]], 1);
    }
}

__global__ void node_prep(const int* __restrict__ indeg, const int* __restrict__ outdeg,
                          float* __restrict__ dis, float* __restrict__ degf) {
    int n = blockIdx.x * blockDim.x + threadIdx.x;
    if (n < NN) {
        dis[n]  = 1.0f / sqrtf(1.0f + (float)indeg[n]);
        degf[n] = (float)outdeg[n];
    }
}

// ---------------- 3-phase multi-block exclusive scan ----------------
__global__ void scan_p1(const int* __restrict__ in, int* __restrict__ part, int n) {
    __shared__ int tile[256];
    int t = threadIdx.x;
    int i = blockIdx.x * 256 + t;
    tile[t] = (i < n) ? in[i] : 0;
    __syncthreads();
    for (int o = 128; o > 0; o >>= 1) {
        if (t < o) tile[t] += tile[t + o];
        __syncthreads();
    }
    if (t == 0) part[blockIdx.x] = tile[0];
}

__global__ void scan_p2(int* __restrict__ part, int nb, int* __restrict__ off_end) {
    __shared__ int tile[256];
    int t = threadIdx.x;
    int v = (t < nb) ? part[t] : 0;
    tile[t] = v;
    __syncthreads();
    for (int o = 1; o < 256; o <<= 1) {
        int x = (t >= o) ? tile[t - o] : 0;
        __syncthreads();
        tile[t] += x;
        __syncthreads();
    }
    if (t < nb) part[t] = tile[t] - v;  // exclusive base per block
    if (t == 255) *off_end = tile[255];
}

__global__ void scan_p3(const int* __restrict__ in, const int* __restrict__ part,
                        int* __restrict__ out, int n) {
    __shared__ int tile[256];
    int t = threadIdx.x;
    int i = blockIdx.x * 256 + t;
    int v = (i < n) ? in[i] : 0;
    tile[t] = v;
    __syncthreads();
    for (int o = 1; o < 256; o <<= 1) {
        int x = (t >= o) ? tile[t - o] : 0;
        __syncthreads();
        tile[t] += x;
        __syncthreads();
    }
    if (i < n) out[i] = part[blockIdx.x] + tile[t] - v;
}

__global__ void scatter_kernel(const int* __restrict__ src, const int* __restrict__ dst,
                               const int* __restrict__ off, int* __restrict__ cur,
                               int* __restrict__ nbr) {
    int e = blockIdx.x * blockDim.x + threadIdx.x;
    if (e < EE) {
        int s = src[e], d = dst[e];
        int p = atomicAdd(&cur[d], 1);
        nbr[off[d] + p] = s;
    }
}

// ---------------- weight transpose + f16 convert: Wt[n][k] = W[k][n] ----------------
__global__ void transpose_w(const float* __restrict__ W, __half* __restrict__ Wt,
                            int Kdim, int Ndim) {
    int i = blockIdx.x * 256 + threadIdx.x;
    if (i < Kdim * Ndim) {
        int k = i / Ndim, n = i % Ndim;
        Wt[(size_t)n * Kdim + k] = __float2half(W[i]);
    }
}

// ---------------- MFMA f16 GEMM: C[M,Nn] = A[M,Kk] @ Bt[n][k]^T ----------------
// Block tile 128x128, 4 waves each 64x64 (4x4 grid of 16x16x32 mfma), K-step 32.
// A: f32 or f16 row-major [M][Kk]; Bt: f16 [Nn][Kk] (pre-transposed); C: f16 [M][Nn].
#define APAD 40  // LDS row stride in halves: 80B, 16B-aligned, 2-way bank alias (free)

__device__ inline void load16h(const float* p, _Float16* o) {
#pragma unroll
    for (int i = 0; i < 16; i += 4) {
        float4 v = *(const float4*)(p + i);
        o[i] = (_Float16)v.x; o[i + 1] = (_Float16)v.y;
        o[i + 2] = (_Float16)v.z; o[i + 3] = (_Float16)v.w;
    }
}
__device__ inline void load16h(const __half* p, _Float16* o) {
    uint4 v0 = *(const uint4*)p;
    uint4 v1 = *(const uint4*)(p + 8);
    *(uint4*)o = v0;
    *(uint4*)(o + 8) = v1;
}

template <typename TA>
__global__ __launch_bounds__(256) void mfma_gemm(const TA* __restrict__ A,
                                                 const __half* __restrict__ Bt,
                                                 __half* __restrict__ C,
                                                 int M, int Nn, int Kk) {
    __shared__ _Float16 As[128][APAD];
    __shared__ _Float16 Bs[128][APAD];
    int t = threadIdx.x;
    int wave = t >> 6, lane = t & 63;
    int quad = lane >> 4, l16 = lane & 15;
    int row0 = blockIdx.y * 128, col0 = blockIdx.x * 128;
    int wm = (wave & 1) * 64, wn = (wave >> 1) * 64;

    f32x4 acc[4][4] = {};

    int sr = t >> 1;         // staging row 0..127
    int sk = (t & 1) * 16;   // staging k-offset 0 or 16

    for (int k0 = 0; k0 < Kk; k0 += 32) {
        // stage A tile [128][32]
        {
            _Float16 tmp[16];
            int gr = row0 + sr;
            if (gr < M) {
                load16h(A + (size_t)gr * Kk + k0 + sk, tmp);
            } else {
#pragma unroll
                for (int i = 0; i < 16; i++) tmp[i] = (_Float16)0.f;
            }
            *(uint4*)&As[sr][sk] = *(uint4*)tmp;
            *(uint4*)&As[sr][sk + 8] = *(uint4*)(tmp + 8);
        }
        // stage B tile [128][32] from Bt rows (col0+sr)
        {
            _Float16 tmp[16];
            load16h(Bt + (size_t)(col0 + sr) * Kk + k0 + sk, tmp);
            *(uint4*)&Bs[sr][sk] = *(uint4*)tmp;
            *(uint4*)&Bs[sr][sk + 8] = *(uint4*)(tmp + 8);
        }
        __syncthreads();

        half8_t af[4], bf[4];
#pragma unroll
        for (int mi = 0; mi < 4; mi++)
            af[mi] = *(const half8_t*)&As[wm + mi * 16 + l16][quad * 8];
#pragma unroll
        for (int ni = 0; ni < 4; ni++)
            bf[ni] = *(const half8_t*)&Bs[wn + ni * 16 + l16][quad * 8];
#pragma unroll
        for (int mi = 0; mi < 4; mi++)
#pragma unroll
            for (int ni = 0; ni < 4; ni++)
                acc[mi][ni] = __builtin_amdgcn_mfma_f32_16x16x32_f16(
                    af[mi], bf[ni], acc[mi][ni], 0, 0, 0);
        __syncthreads();
    }

    // write C: tile (mi,ni), reg r -> row=quad*4+r, col=l16
#pragma unroll
    for (int mi = 0; mi < 4; mi++) {
#pragma unroll
        for (int r = 0; r < 4; r++) {
            int rr = row0 + wm + mi * 16 + quad * 4 + r;
            if (rr < M) {
#pragma unroll
                for (int ni = 0; ni < 4; ni++) {
                    C[(size_t)rr * Nn + col0 + wn + ni * 16 + l16] =
                        __float2half(acc[mi][ni][r]);
                }
            }
        }
    }
}

// ---------------- aggregation + bias + SELU (+optional skip) ----------------
// Half-wave (32 lanes) per node, 8 channels/lane (16B loads), 8 nodes/block.
// Neighbor id/weight broadcast via width-32 shuffles (no LDS, no barrier).
__device__ inline void acc8(float* acc, const __half* p, float w) {
    uint4 raw = *(const uint4*)p;  // 8 halves, 16B
    const __half2* h = (const __half2*)&raw;
#pragma unroll
    for (int i = 0; i < 4; i++) {
        float2 f = __half22float2(h[i]);
        acc[2 * i]     += w * f.x;
        acc[2 * i + 1] += w * f.y;
    }
}

__global__ __launch_bounds__(256) void agg_selu(const __half* __restrict__ T,
                                                const float* __restrict__ dis,
                                                const int* __restrict__ off,
                                                const int* __restrict__ nbr,
                                                const float* __restrict__ bias,
                                                const __half* skip, __half* out) {
    int t = threadIdx.x;
    int lane = t & 63;
    int l32 = lane & 31;
    int n = blockIdx.x * 8 + (t >> 5);  // (wave<<1) + half_id
    int c = l32 * 8;
    float dn = dis[n];

    float acc[8];
    acc8_init: ;
#pragma unroll
    for (int i = 0; i < 8; i++) acc[i] = 0.f;
    // self-loop term
    acc8(acc, T + (size_t)n * HH + c, dn * dn);

    int s0 = off[n], s1 = off[n + 1];
    int sidv = 0;
    float sdsv = 0.f;
    for (int base = s0; base < s1; base += 32) {
        int cnt = min(32, s1 - base);
        if (l32 < cnt) {
            sidv = nbr[base + l32];
            sdsv = dis[sidv] * dn;
        }
        for (int j = 0; j < cnt; j++) {
            int s = __shfl(sidv, j, 32);
            float w = __shfl(sdsv, j, 32);
            acc8(acc, T + (size_t)s * HH + c, w);
        }
    }

    const float scale = 1.0507009873554805f;
    const float alpha = 1.6732632423543772f;
    float4 b0 = *(const float4*)(bias + c);
    float4 b1 = *(const float4*)(bias + c + 4);
    float bb[8] = {b0.x, b0.y, b0.z, b0.w, b1.x, b1.y, b1.z, b1.w};
    float sk8[8];
#pragma unroll
    for (int i = 0; i < 8; i++) sk8[i] = 0.f;
    if (skip) {
        uint4 raw = *(const uint4*)(skip + (size_t)n * HH + c);
        const __half2* h = (const __half2*)&raw;
#pragma unroll
        for (int i = 0; i < 4; i++) {
            float2 f = __half22float2(h[i]);
            sk8[2 * i] = f.x; sk8[2 * i + 1] = f.y;
        }
    }
    _Float16 res[8];
#pragma unroll
    for (int i = 0; i < 8; i++) {
        float v = acc[i] + bb[i];
        float r = v > 0.f ? scale * v : scale * alpha * expm1f(v);
        res[i] = (_Float16)(r + sk8[i]);
    }
    *(uint4*)(out + (size_t)n * HH + c) = *(uint4*)res;
}

// ---------------- assignment head: logits -> softmax -> out + loss partials ----------------
__global__ __launch_bounds__(256) void assign_kernel(const __half* __restrict__ X,
                                                     const float* __restrict__ Wa,
                                                     const float* __restrict__ ba,
                                                     const float* __restrict__ degf,
                                                     float* __restrict__ out_assign,
                                                     float* __restrict__ scal) {
    __shared__ float sWa[HH * KK];   // 16 KB
    __shared__ float sX[16][HH];     // 16 KB
    __shared__ float scs[KK], sdS[KK], sent_s;
    int t = threadIdx.x;
    int nb = blockIdx.x * 16;
    for (int i = t; i < HH * KK; i += 256) sWa[i] = Wa[i];
    for (int r = 0; r < 16; r++) sX[r][t] = __half2float(X[(size_t)(nb + r) * HH + t]);
    if (t < KK) { scs[t] = 0.f; sdS[t] = 0.f; }
    if (t == 0) sent_s = 0.f;
    __syncthreads();

    int k = t & 15, nl = t >> 4;
    float logit = ba[k];
    for (int c = 0; c < HH; c++) logit += sX[nl][c] * sWa[c * KK + k];

    float mx = logit;
    for (int o = 1; o < 16; o <<= 1) mx = fmaxf(mx, __shfl_xor(mx, o, 16));
    float e = expf(logit - mx);
    float sum = e;
    for (int o = 1; o < 16; o <<= 1) sum += __shfl_xor(sum, o, 16);
    float a = e / sum;
    int node = nb + nl;
    out_assign[(size_t)node * KK + k] = a;

    atomicAdd(&scs[k], a);
    atomicAdd(&sdS[k], degf[node] * a);
    float ent = a * logf(a + 1e-8f);
    for (int o = 32; o >= 1; o >>= 1) ent += __shfl_xor(ent, o);
    if ((t & 63) == 0) atomicAdd(&sent_s, ent);
    __syncthreads();
    if (t < KK) {
        atomicAdd(&scal[t], scs[t]);
        atomicAdd(&scal[16 + t], sdS[t]);
    }
    if (t == 0) atomicAdd(&scal[33], sent_s);
}

// ---------------- fused trace(S^T A S) = sum over edges <a_src, a_dst> ----------------
__global__ __launch_bounds__(256) void edge_trace(const int* __restrict__ src,
                                                  const int* __restrict__ dst,
                                                  const float* __restrict__ assign,
                                                  float* __restrict__ scal) {
    int e = blockIdx.x * blockDim.x + threadIdx.x;
    float p = 0.f;
    if (e < EE) {
        int s = src[e], d = dst[e];
        const float4* pa = (const float4*)(assign + (size_t)s * KK);
        const float4* pb = (const float4*)(assign + (size_t)d * KK);
#pragma unroll
        for (int i = 0; i < 4; i++) {
            float4 x = pa[i], y = pb[i];
            p += x.x * y.x + x.y * y.y + x.z * y.z + x.w * y.w;
        }
    }
    for (int o = 32; o >= 1; o >>= 1) p += __shfl_xor(p, o);
    __shared__ float sp;
    if (threadIdx.x == 0) sp = 0.f;
    __syncthreads();
    if ((threadIdx.x & 63) == 0) atomicAdd(&sp, p);
    __syncthreads();
    if (threadIdx.x == 0) atomicAdd(&scal[32], sp);
}

// ---------------- pooled partial: pool_acc[k][d] += sum_n a[n][k]*emb[n][d] ----------------
#define PCHUNK 250
__global__ __launch_bounds__(256) void pooled_partial(const float* __restrict__ emb,
                                                      const float* __restrict__ assign,
                                                      float* __restrict__ pool_acc) {
    int d = blockIdx.x * 256 + threadIdx.x;
    int c0 = blockIdx.y * PCHUNK;
    float acc[KK];
#pragma unroll
    for (int k = 0; k < KK; k++) acc[k] = 0.f;
    __shared__ float sa[128 * KK];  // 8 KB
    for (int sub = 0; sub < PCHUNK; sub += 128) {
        int cnt = min(128, PCHUNK - sub);
        for (int i = threadIdx.x; i < cnt * KK; i += 256)
            sa[i] = assign[(size_t)(c0 + sub) * KK + i];
        __syncthreads();
        for (int j = 0; j < cnt; j++) {
            float ev = emb[(size_t)(c0 + sub + j) * DD + d];
#pragma unroll
            for (int k = 0; k < KK; k++) acc[k] += sa[j * KK + k] * ev;
        }
        __syncthreads();
    }
#pragma unroll
    for (int k = 0; k < KK; k++) atomicAdd(&pool_acc[k * DD + d], acc[k]);
}

// ---------------- finalize: pooled normalize + scalar losses ----------------
__global__ void finalize(const float* __restrict__ pool_acc, const float* __restrict__ scal,
                         float* __restrict__ out) {
    int bx = blockIdx.x, t = threadIdx.x;
    if (bx < 32) {
        int i = bx * 256 + t;  // 0..8191
        int k = i / DD;
        out[800000 + i] = pool_acc[i] / (scal[k] + 1e-8f);
    } else if (t == 0) {
        float cs2 = 0.f, ds2 = 0.f;
        for (int k = 0; k < KK; k++) {
            cs2 += scal[k] * scal[k];
            ds2 += scal[16 + k] * scal[16 + k];
        }
        float two_m = (float)EE;  // sum(degrees) == E, 2m == E
        float normalizer = ds2 / two_m;
        float trace = scal[32];
        float spectral = -(trace - (float)KK * normalizer) / two_m;
        float collapse = sqrtf(cs2) / (float)NN * 4.0f - 1.0f;  // sqrt(K)=4
        float entl = 0.1f * scal[33] / (float)NN;
        out[808192] = spectral;
        out[808193] = collapse;  // COLLAPSE_REG = 1.0
        out[808194] = spectral + collapse + entl;
        out[808195] = entl;
    }
}

extern "C" void kernel_launch(void* const* d_in, const int* in_sizes, int n_in,
                              void* d_out, int out_size, void* d_ws, size_t ws_size,
                              hipStream_t stream) {
    const float* emb = (const float*)d_in[0];
    const int* esrc  = (const int*)d_in[1];
    const int* edst  = (const int*)d_in[2];
    const float* W1  = (const float*)d_in[3];
    const float* b1  = (const float*)d_in[4];
    const float* W2  = (const float*)d_in[5];
    const float* b2  = (const float*)d_in[6];
    const float* Wa  = (const float*)d_in[7];
    const float* ba  = (const float*)d_in[8];
    float* out = (float*)d_out;

    // workspace layout (4B units unless noted) — total ~56 MB
    int* indeg      = (int*)d_ws;            // 50000
    int* outdeg     = indeg + 50000;         // 50000
    int* cur        = outdeg + 50000;        // 50000
    float* pool_acc = (float*)(cur + 50000); // 8192
    float* scal     = pool_acc + 8192;       // 64
    int* part       = (int*)(scal + 64);     // 256 (scan partials)
    int* off        = part + 256;            // 50001 (+pad to 50004)
    int* nbr        = off + 50004;           // 800000
    float* dis      = (float*)(nbr + 800000);// 50000
    float* degf     = dis + 50000;           // 50000
    __half* Wt1     = (__half*)(degf + 50000);   // 256*512 f16
    __half* Wt2     = Wt1 + 256 * 512;           // 256*256 f16
    __half* T       = Wt2 + 256 * 256;           // 50000*256 f16 (25.6 MB)
    __half* Hb      = T + (size_t)NN * HH;       // 50000*256 f16 (25.6 MB)

    // zero the atomically-accumulated region: indeg/outdeg/cur/pool_acc/scal
    zero_kernel<<<dim3(619), 256, 0, stream>>>((int*)d_ws, 158256);
    count_kernel<<<dim3(3125), 256, 0, stream>>>(esrc, edst, indeg, outdeg);
    node_prep<<<dim3(196), 256, 0, stream>>>(indeg, outdeg, dis, degf);

    // CSR offsets: 3-phase scan
    scan_p1<<<dim3(NB_SCAN), 256, 0, stream>>>(indeg, part, NN);
    scan_p2<<<dim3(1), 256, 0, stream>>>(part, NB_SCAN, off + NN);
    scan_p3<<<dim3(NB_SCAN), 256, 0, stream>>>(indeg, part, off, NN);
    scatter_kernel<<<dim3(3125), 256, 0, stream>>>(esrc, edst, off, cur, nbr);

    // weights -> f16 transposed
    transpose_w<<<dim3(512), 256, 0, stream>>>(W1, Wt1, DD, HH);
    transpose_w<<<dim3(256), 256, 0, stream>>>(W2, Wt2, HH, HH);

    // conv1: T = emb @ W1 ; Hb = selu(Ahat*T + b1)
    mfma_gemm<float><<<dim3(2, 391), 256, 0, stream>>>(emb, Wt1, T, NN, HH, DD);
    agg_selu<<<dim3(6250), 256, 0, stream>>>(T, dis, off, nbr, b1, nullptr, Hb);

    // conv2: T = Hb @ W2 ; Hb = selu(Ahat*T + b2) + Hb (skip, in place)
    mfma_gemm<__half><<<dim3(2, 391), 256, 0, stream>>>(Hb, Wt2, T, NN, HH, HH);
    agg_selu<<<dim3(6250), 256, 0, stream>>>(T, dis, off, nbr, b2, Hb, Hb);

    // head: assignments -> d_out[0..800000), loss partials
    assign_kernel<<<dim3(3125), 256, 0, stream>>>(Hb, Wa, ba, degf, out, scal);
    edge_trace<<<dim3(3125), 256, 0, stream>>>(esrc, edst, out, scal);
    pooled_partial<<<dim3(2, 200), 256, 0, stream>>>(emb, out, pool_acc);
    finalize<<<dim3(33), 256, 0, stream>>>(pool_acc, scal, out);
}

// Round 5
// 642.346 us; speedup vs baseline: 1.6607x; 1.0133x over previous
//
#include <hip/hip_runtime.h>
#include <hip/hip_fp16.h>
#include <math.h>

#define NN 50000
#define EE 800000
#define DD 512
#define HH 256
#define KK 16
#define NB_SCAN 196  // ceil(NN/256)

typedef _Float16 half8_t __attribute__((ext_vector_type(8)));
typedef float f32x4 __attribute__((ext_vector_type(4)));

// ---------------- utility ----------------
__global__ void zero_kernel(int* __restrict__ p, int n) {
    int i = blockIdx.x * blockDim.x + threadIdx.x;
    if (i < n) p[i] = 0;
}

__global__ void count_kernel(const int4* __restrict__ src4, const int4* __restrict__ dst4,
                             int* __restrict__ indeg, int* __restrict__ outdeg) {
    int e = blockIdx.x * blockDim.x + threadIdx.x;
    if (e < EE / 4) {
        int4 s = src4[e], d = dst4[e];
        atomicAdd(&outdeg[s.x], 1); atomicAdd(&outdeg[s.y], 1);
        atomicAdd(&outdeg[s.z], 1); atomicAdd(&outdeg[s.w], 1);
        atomicAdd(&indeg[d.x], 1);  atomicAdd(&indeg[d.y], 1);
        atomicAdd(&indeg[d.z], 1);  atomicAdd(&indeg[d.w], 1);
    }
}

// ---------------- 3-phase multi-block exclusive scan (+node_prep fused in p1) ----------------
__global__ void scan_p1(const int* __restrict__ in, int* __restrict__ part, int n,
                        const int* __restrict__ outdeg, float* __restrict__ dis,
                        float* __restrict__ degf) {
    __shared__ int tile[256];
    int t = threadIdx.x;
    int i = blockIdx.x * 256 + t;
    int v = (i < n) ? in[i] : 0;
    tile[t] = v;
    if (i < n) {
        dis[i]  = 1.0f / sqrtf(1.0f + (float)v);
        degf[i] = (float)outdeg[i];
    }
    __syncthreads();
    for (int o = 128; o > 0; o >>= 1) {
        if (t < o) tile[t] += tile[t + o];
        __syncthreads();
    }
    if (t == 0) part[blockIdx.x] = tile[0];
}

__global__ void scan_p2(int* __restrict__ part, int nb, int* __restrict__ off_end) {
    __shared__ int tile[256];
    int t = threadIdx.x;
    int v = (t < nb) ? part[t] : 0;
    tile[t] = v;
    __syncthreads();
    for (int o = 1; o < 256; o <<= 1) {
        int x = (t >= o) ? tile[t - o] : 0;
        __syncthreads();
        tile[t] += x;
        __syncthreads();
    }
    if (t < nb) part[t] = tile[t] - v;  // exclusive base per block
    if (t == 255) *off_end = tile[255];
}

__global__ void scan_p3(const int* __restrict__ in, const int* __restrict__ part,
                        int* __restrict__ out, int n) {
    __shared__ int tile[256];
    int t = threadIdx.x;
    int i = blockIdx.x * 256 + t;
    int v = (i < n) ? in[i] : 0;
    tile[t] = v;
    __syncthreads();
    for (int o = 1; o < 256; o <<= 1) {
        int x = (t >= o) ? tile[t - o] : 0;
        __syncthreads();
        tile[t] += x;
        __syncthreads();
    }
    if (i < n) out[i] = part[blockIdx.x] + tile[t] - v;
}

__global__ void scatter_kernel(const int4* __restrict__ src4, const int4* __restrict__ dst4,
                               const int* __restrict__ off, int* __restrict__ cur,
                               int* __restrict__ nbr) {
    int e = blockIdx.x * blockDim.x + threadIdx.x;
    if (e < EE / 4) {
        int4 s = src4[e], d = dst4[e];
        int p;
        p = atomicAdd(&cur[d.x], 1); nbr[off[d.x] + p] = s.x;
        p = atomicAdd(&cur[d.y], 1); nbr[off[d.y] + p] = s.y;
        p = atomicAdd(&cur[d.z], 1); nbr[off[d.z] + p] = s.z;
        p = atomicAdd(&cur[d.w], 1); nbr[off[d.w] + p] = s.w;
    }
}

// ---------------- fused weight transpose + f16 convert ----------------
__global__ void transpose_w(const float* __restrict__ W1, __half* __restrict__ Wt1,
                            const float* __restrict__ W2, __half* __restrict__ Wt2) {
    int i = blockIdx.x * 256 + threadIdx.x;
    if (i < DD * HH) {
        int k = i / HH, n = i % HH;
        Wt1[(size_t)n * DD + k] = __float2half(W1[i]);
    } else {
        int j = i - DD * HH;
        int k = j / HH, n = j % HH;
        Wt2[(size_t)n * HH + k] = __float2half(W2[j]);
    }
}

// ---------------- MFMA f16 GEMM: C[M,256] = A[M,KDIM] @ Wt[256,KDIM]^T ----------------
// Block tile 128x128, 4 waves x (64x64), 16x16x32 mfma, K-step 32.
// A staged in double-buffered LDS w/ register prefetch; B fragments direct from
// global (weights are L2-resident). One barrier per K-iter.
// grid (392, 2): 392 % 8 == 0 so both col-blocks of a row-tile share an XCD.
template <typename TA, int KDIM>
__global__ __launch_bounds__(256) void mfma_gemm(const TA* __restrict__ A,
                                                 const __half* __restrict__ Bt,
                                                 __half* __restrict__ C, int M) {
    constexpr bool F32 = sizeof(TA) == 4;
    constexpr int SROW = F32 ? 36 : 40;  // LDS row stride (elements): 2-way bank alias max
    constexpr int EPG  = F32 ? 4 : 8;    // elements per 16B granule
    constexpr int GPR  = 32 / EPG;       // granules per k-row of 32
    constexpr int RPP  = 256 / GPR;      // rows staged per pass
    constexpr int NP   = 128 / RPP;      // staging passes
    constexpr int KI   = KDIM / 32;

    __shared__ TA As[2][128 * SROW];

    int t = threadIdx.x;
    int wave = t >> 6, lane = t & 63, quad = lane >> 4, l16 = lane & 15;
    int row0 = blockIdx.x * 128, col0 = blockIdx.y * 128;
    int wm = (wave & 1) * 64, wn = (wave >> 1) * 64;
    int srow = t / GPR, sg = t % GPR;

    f32x4 acc[4][4] = {};
    uint4 sreg[NP];
    uint4 bcur[4];

    const __half* brow[4];
#pragma unroll
    for (int ni = 0; ni < 4; ni++)
        brow[ni] = Bt + (size_t)(col0 + wn + ni * 16 + l16) * KDIM + quad * 8;

    auto gloadA = [&](int k0) {
#pragma unroll
        for (int p = 0; p < NP; p++) {
            int gr = row0 + p * RPP + srow;
            if (gr < M)
                sreg[p] = *(const uint4*)(A + (size_t)gr * KDIM + k0 + sg * EPG);
            else
                sreg[p] = make_uint4(0, 0, 0, 0);
        }
    };
    auto sstore = [&](int buf) {
#pragma unroll
        for (int p = 0; p < NP; p++)
            *(uint4*)&As[buf][(p * RPP + srow) * SROW + sg * EPG] = sreg[p];
    };

    gloadA(0);
#pragma unroll
    for (int ni = 0; ni < 4; ni++) bcur[ni] = *(const uint4*)(brow[ni]);
    sstore(0);
    __syncthreads();

#pragma unroll
    for (int i = 0; i < KI; i++) {
        int cur = i & 1;
        uint4 bnext[4];
        if (i + 1 < KI) {
            gloadA((i + 1) * 32);
#pragma unroll
            for (int ni = 0; ni < 4; ni++)
                bnext[ni] = *(const uint4*)(brow[ni] + (i + 1) * 32);
        }

        half8_t af[4];
#pragma unroll
        for (int mi = 0; mi < 4; mi++) {
            int row = wm + mi * 16 + l16;
            if constexpr (F32) {
                const float* pl = (const float*)&As[cur][0] + row * SROW + quad * 8;
                float4 x0 = *(const float4*)pl;
                float4 x1 = *(const float4*)(pl + 4);
                half8_t h;
                h[0] = (_Float16)x0.x; h[1] = (_Float16)x0.y;
                h[2] = (_Float16)x0.z; h[3] = (_Float16)x0.w;
                h[4] = (_Float16)x1.x; h[5] = (_Float16)x1.y;
                h[6] = (_Float16)x1.z; h[7] = (_Float16)x1.w;
                af[mi] = h;
            } else {
                af[mi] = *(const half8_t*)&As[cur][row * SROW + quad * 8];
            }
        }
#pragma unroll
        for (int mi = 0; mi < 4; mi++)
#pragma unroll
            for (int ni = 0; ni < 4; ni++)
                acc[mi][ni] = __builtin_amdgcn_mfma_f32_16x16x32_f16(
                    af[mi], *(half8_t*)&bcur[ni], acc[mi][ni], 0, 0, 0);

        if (i + 1 < KI) {
            sstore(cur ^ 1);
#pragma unroll
            for (int ni = 0; ni < 4; ni++) bcur[ni] = bnext[ni];
        }
        __syncthreads();
    }

#pragma unroll
    for (int mi = 0; mi < 4; mi++) {
#pragma unroll
        for (int r = 0; r < 4; r++) {
            int rr = row0 + wm + mi * 16 + quad * 4 + r;
            if (rr < M) {
#pragma unroll
                for (int ni = 0; ni < 4; ni++) {
                    C[(size_t)rr * HH + col0 + wn + ni * 16 + l16] =
                        __float2half(acc[mi][ni][r]);
                }
            }
        }
    }
}

// ---------------- aggregation + bias + SELU (+optional skip) ----------------
// Half-wave (32 lanes) per node, 8 ch/lane (16B loads), 8 nodes/block.
// Neighbor loop unrolled x4 with loads batched ahead of FMAs for MLP.
__device__ inline void fma8(float* acc, uint4 raw, float w) {
    const __half2* h = (const __half2*)&raw;
#pragma unroll
    for (int i = 0; i < 4; i++) {
        float2 f = __half22float2(h[i]);
        acc[2 * i]     += w * f.x;
        acc[2 * i + 1] += w * f.y;
    }
}

__global__ __launch_bounds__(256) void agg_selu(const __half* __restrict__ T,
                                                const float* __restrict__ dis,
                                                const int* __restrict__ off,
                                                const int* __restrict__ nbr,
                                                const float* __restrict__ bias,
                                                const __half* skip, __half* out) {
    int t = threadIdx.x;
    int l32 = t & 31;
    int n = blockIdx.x * 8 + (t >> 5);
    int c = l32 * 8;
    float dn = dis[n];

    float acc[8];
#pragma unroll
    for (int i = 0; i < 8; i++) acc[i] = 0.f;
    fma8(acc, *(const uint4*)(T + (size_t)n * HH + c), dn * dn);  // self-loop

    int s0 = off[n], s1 = off[n + 1];
    for (int base = s0; base < s1; base += 32) {
        int cnt = min(32, s1 - base);
        int sidv = 0; float sdsv = 0.f;
        if (l32 < cnt) {
            sidv = nbr[base + l32];
            sdsv = dis[sidv] * dn;
        }
        int j = 0;
        for (; j + 4 <= cnt; j += 4) {
            int a0 = __shfl(sidv, j, 32),     a1 = __shfl(sidv, j + 1, 32);
            int a2 = __shfl(sidv, j + 2, 32), a3 = __shfl(sidv, j + 3, 32);
            float w0 = __shfl(sdsv, j, 32),     w1 = __shfl(sdsv, j + 1, 32);
            float w2 = __shfl(sdsv, j + 2, 32), w3 = __shfl(sdsv, j + 3, 32);
            uint4 r0 = *(const uint4*)(T + (size_t)a0 * HH + c);
            uint4 r1 = *(const uint4*)(T + (size_t)a1 * HH + c);
            uint4 r2 = *(const uint4*)(T + (size_t)a2 * HH + c);
            uint4 r3 = *(const uint4*)(T + (size_t)a3 * HH + c);
            fma8(acc, r0, w0); fma8(acc, r1, w1);
            fma8(acc, r2, w2); fma8(acc, r3, w3);
        }
        for (; j < cnt; j++) {
            int s = __shfl(sidv, j, 32);
            float w = __shfl(sdsv, j, 32);
            fma8(acc, *(const uint4*)(T + (size_t)s * HH + c), w);
        }
    }

    const float scale = 1.0507009873554805f;
    const float alpha = 1.6732632423543772f;
    float4 b0 = *(const float4*)(bias + c);
    float4 b1 = *(const float4*)(bias + c + 4);
    float bb[8] = {b0.x, b0.y, b0.z, b0.w, b1.x, b1.y, b1.z, b1.w};
    float sk8[8];
#pragma unroll
    for (int i = 0; i < 8; i++) sk8[i] = 0.f;
    if (skip) {
        uint4 raw = *(const uint4*)(skip + (size_t)n * HH + c);
        const __half2* h = (const __half2*)&raw;
#pragma unroll
        for (int i = 0; i < 4; i++) {
            float2 f = __half22float2(h[i]);
            sk8[2 * i] = f.x; sk8[2 * i + 1] = f.y;
        }
    }
    _Float16 res[8];
#pragma unroll
    for (int i = 0; i < 8; i++) {
        float v = acc[i] + bb[i];
        float r = v > 0.f ? scale * v : scale * alpha * expm1f(v);
        res[i] = (_Float16)(r + sk8[i]);
    }
    *(uint4*)(out + (size_t)n * HH + c) = *(uint4*)res;
}

// ---------------- assignment head: softmax -> out (+f16 copy) + loss partials ----------------
__global__ __launch_bounds__(256) void assign_kernel(const __half* __restrict__ X,
                                                     const float* __restrict__ Wa,
                                                     const float* __restrict__ ba,
                                                     const float* __restrict__ degf,
                                                     float* __restrict__ out_assign,
                                                     __half* __restrict__ out_f16,
                                                     float* __restrict__ scal) {
    __shared__ float sWa[HH * KK];   // 16 KB
    __shared__ float sX[16][HH];     // 16 KB
    __shared__ float scs[KK], sdS[KK], sent_s;
    int t = threadIdx.x;
    int nb = blockIdx.x * 16;
    for (int i = t; i < HH * KK; i += 256) sWa[i] = Wa[i];
    for (int r = 0; r < 16; r++) sX[r][t] = __half2float(X[(size_t)(nb + r) * HH + t]);
    if (t < KK) { scs[t] = 0.f; sdS[t] = 0.f; }
    if (t == 0) sent_s = 0.f;
    __syncthreads();

    int k = t & 15, nl = t >> 4;
    float logit = ba[k];
    for (int c = 0; c < HH; c++) logit += sX[nl][c] * sWa[c * KK + k];

    float mx = logit;
    for (int o = 1; o < 16; o <<= 1) mx = fmaxf(mx, __shfl_xor(mx, o, 16));
    float e = expf(logit - mx);
    float sum = e;
    for (int o = 1; o < 16; o <<= 1) sum += __shfl_xor(sum, o, 16);
    float a = e / sum;
    int node = nb + nl;
    out_assign[(size_t)node * KK + k] = a;
    out_f16[(size_t)node * KK + k] = __float2half(a);

    atomicAdd(&scs[k], a);
    atomicAdd(&sdS[k], degf[node] * a);
    float ent = a * logf(a + 1e-8f);
    for (int o = 32; o >= 1; o >>= 1) ent += __shfl_xor(ent, o);
    if ((t & 63) == 0) atomicAdd(&sent_s, ent);
    __syncthreads();
    if (t < KK) {
        atomicAdd(&scal[t], scs[t]);
        atomicAdd(&scal[16 + t], sdS[t]);
    }
    if (t == 0) atomicAdd(&scal[33], sent_s);
}

// ---------------- fused trace(S^T A S) over edges, f16 assignments ----------------
__global__ __launch_bounds__(256) void edge_trace(const int* __restrict__ src,
                                                  const int* __restrict__ dst,
                                                  const __half* __restrict__ Ah,
                                                  float* __restrict__ scal) {
    int e = blockIdx.x * blockDim.x + threadIdx.x;
    float p = 0.f;
    if (e < EE) {
        int s = src[e], d = dst[e];
        uint4 sa = *(const uint4*)(Ah + (size_t)s * KK);
        uint4 sb = *(const uint4*)(Ah + (size_t)s * KK + 8);
        uint4 da = *(const uint4*)(Ah + (size_t)d * KK);
        uint4 db = *(const uint4*)(Ah + (size_t)d * KK + 8);
        const __half2* xs = (const __half2*)&sa;
        const __half2* xd = (const __half2*)&da;
#pragma unroll
        for (int i = 0; i < 4; i++) {
            float2 u = __half22float2(xs[i]), v = __half22float2(xd[i]);
            p += u.x * v.x + u.y * v.y;
        }
        xs = (const __half2*)&sb; xd = (const __half2*)&db;
#pragma unroll
        for (int i = 0; i < 4; i++) {
            float2 u = __half22float2(xs[i]), v = __half22float2(xd[i]);
            p += u.x * v.x + u.y * v.y;
        }
    }
    for (int o = 32; o >= 1; o >>= 1) p += __shfl_xor(p, o);
    __shared__ float sp;
    if (threadIdx.x == 0) sp = 0.f;
    __syncthreads();
    if ((threadIdx.x & 63) == 0) atomicAdd(&sp, p);
    __syncthreads();
    if (threadIdx.x == 0) atomicAdd(&scal[32], sp);
}

// ---------------- pooled partial: pool_acc[k][d] += sum_n a[n][k]*emb[n][d] ----------------
#define PCHUNK 250
__global__ __launch_bounds__(256) void pooled_partial(const float* __restrict__ emb,
                                                      const float* __restrict__ assign,
                                                      float* __restrict__ pool_acc) {
    int d = blockIdx.x * 256 + threadIdx.x;
    int c0 = blockIdx.y * PCHUNK;
    float acc[KK];
#pragma unroll
    for (int k = 0; k < KK; k++) acc[k] = 0.f;
    __shared__ float sa[128 * KK];  // 8 KB
    for (int sub = 0; sub < PCHUNK; sub += 128) {
        int cnt = min(128, PCHUNK - sub);
        for (int i = threadIdx.x; i < cnt * KK; i += 256)
            sa[i] = assign[(size_t)(c0 + sub) * KK + i];
        __syncthreads();
        for (int j = 0; j < cnt; j++) {
            float ev = emb[(size_t)(c0 + sub + j) * DD + d];
#pragma unroll
            for (int k = 0; k < KK; k++) acc[k] += sa[j * KK + k] * ev;
        }
        __syncthreads();
    }
#pragma unroll
    for (int k = 0; k < KK; k++) atomicAdd(&pool_acc[k * DD + d], acc[k]);
}

// ---------------- finalize: pooled normalize + scalar losses ----------------
__global__ void finalize(const float* __restrict__ pool_acc, const float* __restrict__ scal,
                         float* __restrict__ out) {
    int bx = blockIdx.x, t = threadIdx.x;
    if (bx < 32) {
        int i = bx * 256 + t;  // 0..8191
        int k = i / DD;
        out[800000 + i] = pool_acc[i] / (scal[k] + 1e-8f);
    } else if (t == 0) {
        float cs2 = 0.f, ds2 = 0.f;
        for (int k = 0; k < KK; k++) {
            cs2 += scal[k] * scal[k];
            ds2 += scal[16 + k] * scal[16 + k];
        }
        float two_m = (float)EE;  // sum(degrees) == E, 2m == E
        float normalizer = ds2 / two_m;
        float trace = scal[32];
        float spectral = -(trace - (float)KK * normalizer) / two_m;
        float collapse = sqrtf(cs2) / (float)NN * 4.0f - 1.0f;  // sqrt(K)=4
        float entl = 0.1f * scal[33] / (float)NN;
        out[808192] = spectral;
        out[808193] = collapse;  // COLLAPSE_REG = 1.0
        out[808194] = spectral + collapse + entl;
        out[808195] = entl;
    }
}

extern "C" void kernel_launch(void* const* d_in, const int* in_sizes, int n_in,
                              void* d_out, int out_size, void* d_ws, size_t ws_size,
                              hipStream_t stream) {
    const float* emb = (const float*)d_in[0];
    const int* esrc  = (const int*)d_in[1];
    const int* edst  = (const int*)d_in[2];
    const float* W1  = (const float*)d_in[3];
    const float* b1  = (const float*)d_in[4];
    const float* W2  = (const float*)d_in[5];
    const float* b2  = (const float*)d_in[6];
    const float* Wa  = (const float*)d_in[7];
    const float* ba  = (const float*)d_in[8];
    float* out = (float*)d_out;

    // workspace layout (4B units unless noted) — total ~56 MB
    int* indeg      = (int*)d_ws;            // 50000
    int* outdeg     = indeg + 50000;         // 50000
    int* cur        = outdeg + 50000;        // 50000
    float* pool_acc = (float*)(cur + 50000); // 8192
    float* scal     = pool_acc + 8192;       // 64
    int* part       = (int*)(scal + 64);     // 256 (scan partials)
    int* off        = part + 256;            // 50001 (+pad to 50004)
    int* nbr        = off + 50004;           // 800000
    float* dis      = (float*)(nbr + 800000);// 50000
    float* degf     = dis + 50000;           // 50000
    __half* Wt1     = (__half*)(degf + 50000);   // 256*512 f16
    __half* Wt2     = Wt1 + 256 * 512;           // 256*256 f16
    __half* T       = Wt2 + 256 * 256;           // 50000*256 f16 (25.6 MB)
    __half* Hb      = T + (size_t)NN * HH;       // 50000*256 f16 (25.6 MB)
    __half* Ah      = T;  // f16 assignments alias T (dead after agg2)

    // zero the atomically-accumulated region: indeg/outdeg/cur/pool_acc/scal
    zero_kernel<<<dim3(619), 256, 0, stream>>>((int*)d_ws, 158256);
    count_kernel<<<dim3(782), 256, 0, stream>>>((const int4*)esrc, (const int4*)edst,
                                                indeg, outdeg);

    // CSR offsets: 3-phase scan (+ dis/degf in p1)
    scan_p1<<<dim3(NB_SCAN), 256, 0, stream>>>(indeg, part, NN, outdeg, dis, degf);
    scan_p2<<<dim3(1), 256, 0, stream>>>(part, NB_SCAN, off + NN);
    scan_p3<<<dim3(NB_SCAN), 256, 0, stream>>>(indeg, part, off, NN);
    scatter_kernel<<<dim3(782), 256, 0, stream>>>((const int4*)esrc, (const int4*)edst,
                                                  off, cur, nbr);

    // weights -> f16 transposed (fused)
    transpose_w<<<dim3(768), 256, 0, stream>>>(W1, Wt1, W2, Wt2);

    // conv1: T = emb @ W1 ; Hb = selu(Ahat*T + b1)
    mfma_gemm<float, DD><<<dim3(392, 2), 256, 0, stream>>>(emb, Wt1, T, NN);
    agg_selu<<<dim3(6250), 256, 0, stream>>>(T, dis, off, nbr, b1, nullptr, Hb);

    // conv2: T = Hb @ W2 ; Hb = selu(Ahat*T + b2) + Hb (skip, in place)
    mfma_gemm<__half, HH><<<dim3(392, 2), 256, 0, stream>>>(Hb, Wt2, T, NN);
    agg_selu<<<dim3(6250), 256, 0, stream>>>(T, dis, off, nbr, b2, Hb, Hb);

    // head: assignments -> d_out[0..800000) (+f16 copy), loss partials
    assign_kernel<<<dim3(3125), 256, 0, stream>>>(Hb, Wa, ba, degf, out, Ah, scal);
    edge_trace<<<dim3(3125), 256, 0, stream>>>(esrc, edst, Ah, scal);
    pooled_partial<<<dim3(2, 200), 256, 0, stream>>>(emb, out, pool_acc);
    finalize<<<dim3(33), 256, 0, stream>>>(pool_acc, scal, out);
}

// Round 6
// 563.849 us; speedup vs baseline: 1.8919x; 1.1392x over previous
//
#include <hip/hip_runtime.h>
#include <hip/hip_fp16.h>
#include <math.h>

#define NN 50000
#define EE 800000
#define DD 512
#define HH 256
#define KK 16
#define NB_SCAN 196  // ceil(NN/256)

typedef _Float16 half8_t __attribute__((ext_vector_type(8)));
typedef float f32x4 __attribute__((ext_vector_type(4)));

// ---------------- utility ----------------
__global__ void zero_kernel(int* __restrict__ p, int n) {
    int i = blockIdx.x * blockDim.x + threadIdx.x;
    if (i < n) p[i] = 0;
}

__global__ void count_kernel(const int4* __restrict__ src4, const int4* __restrict__ dst4,
                             int* __restrict__ indeg, int* __restrict__ outdeg) {
    int e = blockIdx.x * blockDim.x + threadIdx.x;
    if (e < EE / 4) {
        int4 s = src4[e], d = dst4[e];
        atomicAdd(&outdeg[s.x], 1); atomicAdd(&outdeg[s.y], 1);
        atomicAdd(&outdeg[s.z], 1); atomicAdd(&outdeg[s.w], 1);
        atomicAdd(&indeg[d.x], 1);  atomicAdd(&indeg[d.y], 1);
        atomicAdd(&indeg[d.z], 1);  atomicAdd(&indeg[d.w], 1);
    }
}

// ---------------- 3-phase multi-block exclusive scan (+node_prep fused in p1) ----------------
__global__ void scan_p1(const int* __restrict__ in, int* __restrict__ part, int n,
                        const int* __restrict__ outdeg, float* __restrict__ dis,
                        float* __restrict__ degf) {
    __shared__ int tile[256];
    int t = threadIdx.x;
    int i = blockIdx.x * 256 + t;
    int v = (i < n) ? in[i] : 0;
    tile[t] = v;
    if (i < n) {
        dis[i]  = 1.0f / sqrtf(1.0f + (float)v);
        degf[i] = (float)outdeg[i];
    }
    __syncthreads();
    for (int o = 128; o > 0; o >>= 1) {
        if (t < o) tile[t] += tile[t + o];
        __syncthreads();
    }
    if (t == 0) part[blockIdx.x] = tile[0];
}

__global__ void scan_p2(int* __restrict__ part, int nb, int* __restrict__ off_end) {
    __shared__ int tile[256];
    int t = threadIdx.x;
    int v = (t < nb) ? part[t] : 0;
    tile[t] = v;
    __syncthreads();
    for (int o = 1; o < 256; o <<= 1) {
        int x = (t >= o) ? tile[t - o] : 0;
        __syncthreads();
        tile[t] += x;
        __syncthreads();
    }
    if (t < nb) part[t] = tile[t] - v;  // exclusive base per block
    if (t == 255) *off_end = tile[255];
}

__global__ void scan_p3(const int* __restrict__ in, const int* __restrict__ part,
                        int* __restrict__ out, int n) {
    __shared__ int tile[256];
    int t = threadIdx.x;
    int i = blockIdx.x * 256 + t;
    int v = (i < n) ? in[i] : 0;
    tile[t] = v;
    __syncthreads();
    for (int o = 1; o < 256; o <<= 1) {
        int x = (t >= o) ? tile[t - o] : 0;
        __syncthreads();
        tile[t] += x;
        __syncthreads();
    }
    if (i < n) out[i] = part[blockIdx.x] + tile[t] - v;
}

__global__ void scatter_kernel(const int4* __restrict__ src4, const int4* __restrict__ dst4,
                               const int* __restrict__ off, int* __restrict__ cur,
                               int* __restrict__ nbr) {
    int e = blockIdx.x * blockDim.x + threadIdx.x;
    if (e < EE / 4) {
        int4 s = src4[e], d = dst4[e];
        int p;
        p = atomicAdd(&cur[d.x], 1); nbr[off[d.x] + p] = s.x;
        p = atomicAdd(&cur[d.y], 1); nbr[off[d.y] + p] = s.y;
        p = atomicAdd(&cur[d.z], 1); nbr[off[d.z] + p] = s.z;
        p = atomicAdd(&cur[d.w], 1); nbr[off[d.w] + p] = s.w;
    }
}

// ---------------- fused weight transpose + f16 convert (W1, W2, Wa) ----------------
__global__ void transpose_w(const float* __restrict__ W1, __half* __restrict__ Wt1,
                            const float* __restrict__ W2, __half* __restrict__ Wt2,
                            const float* __restrict__ Wa, __half* __restrict__ WaT) {
    int i = blockIdx.x * 256 + threadIdx.x;
    if (i < DD * HH) {
        int k = i / HH, n = i % HH;
        Wt1[(size_t)n * DD + k] = __float2half(W1[i]);
    } else if (i < DD * HH + HH * HH) {
        int j = i - DD * HH;
        int k = j / HH, n = j % HH;
        Wt2[(size_t)n * HH + k] = __float2half(W2[j]);
    } else if (i < DD * HH + HH * HH + HH * KK) {
        int j = i - DD * HH - HH * HH;
        int k = j / KK, n = j % KK;
        WaT[n * HH + k] = __float2half(Wa[j]);
    }
}

// ---------------- MFMA f16 GEMM: C[M,256] = A[M,KDIM] @ Wt[256,KDIM]^T ----------------
template <typename TA, int KDIM>
__global__ __launch_bounds__(256) void mfma_gemm(const TA* __restrict__ A,
                                                 const __half* __restrict__ Bt,
                                                 __half* __restrict__ C, int M) {
    constexpr bool F32 = sizeof(TA) == 4;
    constexpr int SROW = F32 ? 36 : 40;  // LDS row stride: 2-way bank alias max
    constexpr int EPG  = F32 ? 4 : 8;    // elements per 16B granule
    constexpr int GPR  = 32 / EPG;       // granules per k-row of 32
    constexpr int RPP  = 256 / GPR;      // rows staged per pass
    constexpr int NP   = 128 / RPP;      // staging passes
    constexpr int KI   = KDIM / 32;

    __shared__ TA As[2][128 * SROW];

    int t = threadIdx.x;
    int wave = t >> 6, lane = t & 63, quad = lane >> 4, l16 = lane & 15;
    int row0 = blockIdx.x * 128, col0 = blockIdx.y * 128;
    int wm = (wave & 1) * 64, wn = (wave >> 1) * 64;
    int srow = t / GPR, sg = t % GPR;

    f32x4 acc[4][4] = {};
    uint4 sreg[NP];
    uint4 bcur[4];

    const __half* brow[4];
#pragma unroll
    for (int ni = 0; ni < 4; ni++)
        brow[ni] = Bt + (size_t)(col0 + wn + ni * 16 + l16) * KDIM + quad * 8;

    auto gloadA = [&](int k0) {
#pragma unroll
        for (int p = 0; p < NP; p++) {
            int gr = row0 + p * RPP + srow;
            if (gr < M)
                sreg[p] = *(const uint4*)(A + (size_t)gr * KDIM + k0 + sg * EPG);
            else
                sreg[p] = make_uint4(0, 0, 0, 0);
        }
    };
    auto sstore = [&](int buf) {
#pragma unroll
        for (int p = 0; p < NP; p++)
            *(uint4*)&As[buf][(p * RPP + srow) * SROW + sg * EPG] = sreg[p];
    };

    gloadA(0);
#pragma unroll
    for (int ni = 0; ni < 4; ni++) bcur[ni] = *(const uint4*)(brow[ni]);
    sstore(0);
    __syncthreads();

#pragma unroll
    for (int i = 0; i < KI; i++) {
        int cur = i & 1;
        uint4 bnext[4];
        if (i + 1 < KI) {
            gloadA((i + 1) * 32);
#pragma unroll
            for (int ni = 0; ni < 4; ni++)
                bnext[ni] = *(const uint4*)(brow[ni] + (i + 1) * 32);
        }

        half8_t af[4];
#pragma unroll
        for (int mi = 0; mi < 4; mi++) {
            int row = wm + mi * 16 + l16;
            if constexpr (F32) {
                const float* pl = (const float*)&As[cur][0] + row * SROW + quad * 8;
                float4 x0 = *(const float4*)pl;
                float4 x1 = *(const float4*)(pl + 4);
                half8_t h;
                h[0] = (_Float16)x0.x; h[1] = (_Float16)x0.y;
                h[2] = (_Float16)x0.z; h[3] = (_Float16)x0.w;
                h[4] = (_Float16)x1.x; h[5] = (_Float16)x1.y;
                h[6] = (_Float16)x1.z; h[7] = (_Float16)x1.w;
                af[mi] = h;
            } else {
                af[mi] = *(const half8_t*)&As[cur][row * SROW + quad * 8];
            }
        }
#pragma unroll
        for (int mi = 0; mi < 4; mi++)
#pragma unroll
            for (int ni = 0; ni < 4; ni++)
                acc[mi][ni] = __builtin_amdgcn_mfma_f32_16x16x32_f16(
                    af[mi], *(half8_t*)&bcur[ni], acc[mi][ni], 0, 0, 0);

        if (i + 1 < KI) {
            sstore(cur ^ 1);
#pragma unroll
            for (int ni = 0; ni < 4; ni++) bcur[ni] = bnext[ni];
        }
        __syncthreads();
    }

#pragma unroll
    for (int mi = 0; mi < 4; mi++) {
#pragma unroll
        for (int r = 0; r < 4; r++) {
            int rr = row0 + wm + mi * 16 + quad * 4 + r;
            if (rr < M) {
#pragma unroll
                for (int ni = 0; ni < 4; ni++) {
                    C[(size_t)rr * HH + col0 + wn + ni * 16 + l16] =
                        __float2half(acc[mi][ni][r]);
                }
            }
        }
    }
}

// ---------------- aggregation + bias + SELU (+optional skip) ----------------
__device__ inline void fma8(float* acc, uint4 raw, float w) {
    const __half2* h = (const __half2*)&raw;
#pragma unroll
    for (int i = 0; i < 4; i++) {
        float2 f = __half22float2(h[i]);
        acc[2 * i]     += w * f.x;
        acc[2 * i + 1] += w * f.y;
    }
}

__global__ __launch_bounds__(256) void agg_selu(const __half* __restrict__ T,
                                                const float* __restrict__ dis,
                                                const int* __restrict__ off,
                                                const int* __restrict__ nbr,
                                                const float* __restrict__ bias,
                                                const __half* skip, __half* out) {
    int t = threadIdx.x;
    int l32 = t & 31;
    int n = blockIdx.x * 8 + (t >> 5);
    int c = l32 * 8;
    float dn = dis[n];

    float acc[8];
#pragma unroll
    for (int i = 0; i < 8; i++) acc[i] = 0.f;
    fma8(acc, *(const uint4*)(T + (size_t)n * HH + c), dn * dn);  // self-loop

    int s0 = off[n], s1 = off[n + 1];
    for (int base = s0; base < s1; base += 32) {
        int cnt = min(32, s1 - base);
        int sidv = 0; float sdsv = 0.f;
        if (l32 < cnt) {
            sidv = nbr[base + l32];
            sdsv = dis[sidv] * dn;
        }
        int j = 0;
        for (; j + 8 <= cnt; j += 8) {
            int a0 = __shfl(sidv, j, 32),     a1 = __shfl(sidv, j + 1, 32);
            int a2 = __shfl(sidv, j + 2, 32), a3 = __shfl(sidv, j + 3, 32);
            int a4 = __shfl(sidv, j + 4, 32), a5 = __shfl(sidv, j + 5, 32);
            int a6 = __shfl(sidv, j + 6, 32), a7 = __shfl(sidv, j + 7, 32);
            float w0 = __shfl(sdsv, j, 32),     w1 = __shfl(sdsv, j + 1, 32);
            float w2 = __shfl(sdsv, j + 2, 32), w3 = __shfl(sdsv, j + 3, 32);
            float w4 = __shfl(sdsv, j + 4, 32), w5 = __shfl(sdsv, j + 5, 32);
            float w6 = __shfl(sdsv, j + 6, 32), w7 = __shfl(sdsv, j + 7, 32);
            uint4 r0 = *(const uint4*)(T + (size_t)a0 * HH + c);
            uint4 r1 = *(const uint4*)(T + (size_t)a1 * HH + c);
            uint4 r2 = *(const uint4*)(T + (size_t)a2 * HH + c);
            uint4 r3 = *(const uint4*)(T + (size_t)a3 * HH + c);
            uint4 r4 = *(const uint4*)(T + (size_t)a4 * HH + c);
            uint4 r5 = *(const uint4*)(T + (size_t)a5 * HH + c);
            uint4 r6 = *(const uint4*)(T + (size_t)a6 * HH + c);
            uint4 r7 = *(const uint4*)(T + (size_t)a7 * HH + c);
            fma8(acc, r0, w0); fma8(acc, r1, w1);
            fma8(acc, r2, w2); fma8(acc, r3, w3);
            fma8(acc, r4, w4); fma8(acc, r5, w5);
            fma8(acc, r6, w6); fma8(acc, r7, w7);
        }
        for (; j < cnt; j++) {
            int s = __shfl(sidv, j, 32);
            float w = __shfl(sdsv, j, 32);
            fma8(acc, *(const uint4*)(T + (size_t)s * HH + c), w);
        }
    }

    const float scale = 1.0507009873554805f;
    const float alpha = 1.6732632423543772f;
    float4 b0 = *(const float4*)(bias + c);
    float4 b1 = *(const float4*)(bias + c + 4);
    float bb[8] = {b0.x, b0.y, b0.z, b0.w, b1.x, b1.y, b1.z, b1.w};
    float sk8[8];
#pragma unroll
    for (int i = 0; i < 8; i++) sk8[i] = 0.f;
    if (skip) {
        uint4 raw = *(const uint4*)(skip + (size_t)n * HH + c);
        const __half2* h = (const __half2*)&raw;
#pragma unroll
        for (int i = 0; i < 4; i++) {
            float2 f = __half22float2(h[i]);
            sk8[2 * i] = f.x; sk8[2 * i + 1] = f.y;
        }
    }
    _Float16 res[8];
#pragma unroll
    for (int i = 0; i < 8; i++) {
        float v = acc[i] + bb[i];
        float r = v > 0.f ? scale * v : scale * alpha * expm1f(v);
        res[i] = (_Float16)(r + sk8[i]);
    }
    *(uint4*)(out + (size_t)n * HH + c) = *(uint4*)res;
}

// ---------------- assignment head via MFMA ----------------
// Wave = 64 nodes; logits = Hb[64x256] @ WaT[16x256]^T via 4 mfma per K-step.
// C layout: col(l16)=cluster k, row=quad*4+r within each 16-node group mi.
__global__ __launch_bounds__(256) void assign_mfma(const __half* __restrict__ Hb,
                                                   const __half* __restrict__ WaT,
                                                   const float* __restrict__ ba,
                                                   const float* __restrict__ degf,
                                                   float* __restrict__ out_assign,
                                                   __half* __restrict__ out_f16,
                                                   float* __restrict__ scal) {
    int t = threadIdx.x;
    int wave = t >> 6, lane = t & 63, quad = lane >> 4, l16 = lane & 15;
    int nb = blockIdx.x * 256 + wave * 64;

    f32x4 acc[4] = {};
    const __half* bp = WaT + l16 * HH + quad * 8;
    const __half* ap[4];
#pragma unroll
    for (int mi = 0; mi < 4; mi++) {
        int r = nb + mi * 16 + l16;
        if (r >= NN) r = NN - 1;
        ap[mi] = Hb + (size_t)r * HH + quad * 8;
    }
#pragma unroll
    for (int s = 0; s < 8; s++) {
        half8_t bf = *(const half8_t*)(bp + s * 32);
#pragma unroll
        for (int mi = 0; mi < 4; mi++) {
            half8_t af = *(const half8_t*)(ap[mi] + s * 32);
            acc[mi] = __builtin_amdgcn_mfma_f32_16x16x32_f16(af, bf, acc[mi], 0, 0, 0);
        }
    }

    float myb = ba[l16];
    float lcs = 0.f, ldS = 0.f, lent = 0.f;
#pragma unroll
    for (int mi = 0; mi < 4; mi++) {
#pragma unroll
        for (int r = 0; r < 4; r++) {
            int node = nb + mi * 16 + quad * 4 + r;
            bool ok = node < NN;
            float logit = acc[mi][r] + myb;
            float mx = logit;
            for (int o = 1; o < 16; o <<= 1) mx = fmaxf(mx, __shfl_xor(mx, o, 16));
            float e = expf(logit - mx);
            float sum = e;
            for (int o = 1; o < 16; o <<= 1) sum += __shfl_xor(sum, o, 16);
            float a = e / sum;
            if (ok) {
                out_assign[(size_t)node * KK + l16] = a;
                out_f16[(size_t)node * KK + l16] = __float2half(a);
                lcs += a;
                ldS += degf[node] * a;
                lent += a * logf(a + 1e-8f);
            }
        }
    }
    // cs/dS: reduce across the 4 quads (same l16)
    lcs += __shfl_xor(lcs, 16); lcs += __shfl_xor(lcs, 32);
    ldS += __shfl_xor(ldS, 16); ldS += __shfl_xor(ldS, 32);
    for (int o = 32; o >= 1; o >>= 1) lent += __shfl_xor(lent, o);
    if (quad == 0) {
        atomicAdd(&scal[l16], lcs);
        atomicAdd(&scal[16 + l16], ldS);
    }
    if (lane == 0) atomicAdd(&scal[33], lent);
}

// ---------------- fused trace(S^T A S): 4 edges per thread, f16 assignments ----------------
__device__ inline float dot16h(const __half* a, const __half* b) {
    uint4 a0 = *(const uint4*)a, a1 = *(const uint4*)(a + 8);
    uint4 b0 = *(const uint4*)b, b1 = *(const uint4*)(b + 8);
    float p = 0.f;
    const __half2* xa = (const __half2*)&a0;
    const __half2* xb = (const __half2*)&b0;
#pragma unroll
    for (int i = 0; i < 4; i++) {
        float2 u = __half22float2(xa[i]), v = __half22float2(xb[i]);
        p += u.x * v.x + u.y * v.y;
    }
    xa = (const __half2*)&a1; xb = (const __half2*)&b1;
#pragma unroll
    for (int i = 0; i < 4; i++) {
        float2 u = __half22float2(xa[i]), v = __half22float2(xb[i]);
        p += u.x * v.x + u.y * v.y;
    }
    return p;
}

__global__ __launch_bounds__(256) void edge_trace(const int4* __restrict__ src4,
                                                  const int4* __restrict__ dst4,
                                                  const __half* __restrict__ Ah,
                                                  float* __restrict__ scal) {
    int e = blockIdx.x * blockDim.x + threadIdx.x;
    float p = 0.f;
    if (e < EE / 4) {
        int4 s = src4[e], d = dst4[e];
        p += dot16h(Ah + (size_t)s.x * KK, Ah + (size_t)d.x * KK);
        p += dot16h(Ah + (size_t)s.y * KK, Ah + (size_t)d.y * KK);
        p += dot16h(Ah + (size_t)s.z * KK, Ah + (size_t)d.z * KK);
        p += dot16h(Ah + (size_t)s.w * KK, Ah + (size_t)d.w * KK);
    }
    for (int o = 32; o >= 1; o >>= 1) p += __shfl_xor(p, o);
    __shared__ float sp;
    if (threadIdx.x == 0) sp = 0.f;
    __syncthreads();
    if ((threadIdx.x & 63) == 0) atomicAdd(&sp, p);
    __syncthreads();
    if (threadIdx.x == 0) atomicAdd(&scal[32], sp);
}

// ---------------- pooled partial: pool_acc[k][d] += sum_n a[n][k]*emb[n][d] ----------------
#define PCH 125
__global__ __launch_bounds__(256) void pooled_partial(const float* __restrict__ emb,
                                                      const float* __restrict__ assign,
                                                      float* __restrict__ pool_acc) {
    int d = blockIdx.x * 256 + threadIdx.x;
    int c0 = blockIdx.y * PCH;
    float acc[KK];
#pragma unroll
    for (int k = 0; k < KK; k++) acc[k] = 0.f;
    __shared__ float sa[PCH * KK];  // 8 KB
    {
        const float4* srcv = (const float4*)(assign + (size_t)c0 * KK);
        float4* dstv = (float4*)sa;
        for (int i = threadIdx.x; i < PCH * KK / 4; i += 256) dstv[i] = srcv[i];
    }
    __syncthreads();
    for (int j = 0; j < PCH; j++) {
        float ev = emb[(size_t)(c0 + j) * DD + d];
#pragma unroll
        for (int k4 = 0; k4 < 4; k4++) {
            float4 s4 = *(const float4*)&sa[j * KK + k4 * 4];
            acc[k4 * 4 + 0] += s4.x * ev;
            acc[k4 * 4 + 1] += s4.y * ev;
            acc[k4 * 4 + 2] += s4.z * ev;
            acc[k4 * 4 + 3] += s4.w * ev;
        }
    }
#pragma unroll
    for (int k = 0; k < KK; k++) atomicAdd(&pool_acc[k * DD + d], acc[k]);
}

// ---------------- finalize: pooled normalize + scalar losses ----------------
__global__ void finalize(const float* __restrict__ pool_acc, const float* __restrict__ scal,
                         float* __restrict__ out) {
    int bx = blockIdx.x, t = threadIdx.x;
    if (bx < 32) {
        int i = bx * 256 + t;  // 0..8191
        int k = i / DD;
        out[800000 + i] = pool_acc[i] / (scal[k] + 1e-8f);
    } else if (t == 0) {
        float cs2 = 0.f, ds2 = 0.f;
        for (int k = 0; k < KK; k++) {
            cs2 += scal[k] * scal[k];
            ds2 += scal[16 + k] * scal[16 + k];
        }
        float two_m = (float)EE;  // sum(degrees) == E, 2m == E
        float normalizer = ds2 / two_m;
        float trace = scal[32];
        float spectral = -(trace - (float)KK * normalizer) / two_m;
        float collapse = sqrtf(cs2) / (float)NN * 4.0f - 1.0f;  // sqrt(K)=4
        float entl = 0.1f * scal[33] / (float)NN;
        out[808192] = spectral;
        out[808193] = collapse;  // COLLAPSE_REG = 1.0
        out[808194] = spectral + collapse + entl;
        out[808195] = entl;
    }
}

extern "C" void kernel_launch(void* const* d_in, const int* in_sizes, int n_in,
                              void* d_out, int out_size, void* d_ws, size_t ws_size,
                              hipStream_t stream) {
    const float* emb = (const float*)d_in[0];
    const int* esrc  = (const int*)d_in[1];
    const int* edst  = (const int*)d_in[2];
    const float* W1  = (const float*)d_in[3];
    const float* b1  = (const float*)d_in[4];
    const float* W2  = (const float*)d_in[5];
    const float* b2  = (const float*)d_in[6];
    const float* Wa  = (const float*)d_in[7];
    const float* ba  = (const float*)d_in[8];
    float* out = (float*)d_out;

    // workspace layout (4B units unless noted) — total ~56 MB
    int* indeg      = (int*)d_ws;            // 50000
    int* outdeg     = indeg + 50000;         // 50000
    int* cur        = outdeg + 50000;        // 50000
    float* pool_acc = (float*)(cur + 50000); // 8192
    float* scal     = pool_acc + 8192;       // 64
    int* part       = (int*)(scal + 64);     // 256 (scan partials)
    int* off        = part + 256;            // 50001 (+pad to 50004)
    int* nbr        = off + 50004;           // 800000
    float* dis      = (float*)(nbr + 800000);// 50000
    float* degf     = dis + 50000;           // 50000
    __half* Wt1     = (__half*)(degf + 50000);   // 256*512 f16
    __half* Wt2     = Wt1 + 256 * 512;           // 256*256 f16
    __half* WaT     = Wt2 + 256 * 256;           // 16*256 f16
    __half* T       = WaT + 16 * 256;            // 50000*256 f16 (25.6 MB)
    __half* Hb      = T + (size_t)NN * HH;       // 50000*256 f16 (25.6 MB)
    __half* Ah      = T;  // f16 assignments alias T (dead after agg2)

    // zero the atomically-accumulated region: indeg/outdeg/cur/pool_acc/scal
    zero_kernel<<<dim3(619), 256, 0, stream>>>((int*)d_ws, 158256);
    count_kernel<<<dim3(782), 256, 0, stream>>>((const int4*)esrc, (const int4*)edst,
                                                indeg, outdeg);

    // CSR offsets: 3-phase scan (+ dis/degf in p1)
    scan_p1<<<dim3(NB_SCAN), 256, 0, stream>>>(indeg, part, NN, outdeg, dis, degf);
    scan_p2<<<dim3(1), 256, 0, stream>>>(part, NB_SCAN, off + NN);
    scan_p3<<<dim3(NB_SCAN), 256, 0, stream>>>(indeg, part, off, NN);
    scatter_kernel<<<dim3(782), 256, 0, stream>>>((const int4*)esrc, (const int4*)edst,
                                                  off, cur, nbr);

    // weights -> f16 transposed (fused: W1, W2, Wa)
    transpose_w<<<dim3(784), 256, 0, stream>>>(W1, Wt1, W2, Wt2, Wa, WaT);

    // conv1: T = emb @ W1 ; Hb = selu(Ahat*T + b1)
    mfma_gemm<float, DD><<<dim3(392, 2), 256, 0, stream>>>(emb, Wt1, T, NN);
    agg_selu<<<dim3(6250), 256, 0, stream>>>(T, dis, off, nbr, b1, nullptr, Hb);

    // conv2: T = Hb @ W2 ; Hb = selu(Ahat*T + b2) + Hb (skip, in place)
    mfma_gemm<__half, HH><<<dim3(392, 2), 256, 0, stream>>>(Hb, Wt2, T, NN);
    agg_selu<<<dim3(6250), 256, 0, stream>>>(T, dis, off, nbr, b2, Hb, Hb);

    // head: assignments -> d_out[0..800000) (+f16 copy), loss partials
    assign_mfma<<<dim3(196), 256, 0, stream>>>(Hb, WaT, ba, degf, out, Ah, scal);
    edge_trace<<<dim3(782), 256, 0, stream>>>((const int4*)esrc, (const int4*)edst, Ah, scal);
    pooled_partial<<<dim3(2, 400), 256, 0, stream>>>(emb, out, pool_acc);
    finalize<<<dim3(33), 256, 0, stream>>>(pool_acc, scal, out);
}